// Round 3
// baseline (1120.213 us; speedup 1.0000x reference)
//
#include <hip/hip_runtime.h>
#include <hip/hip_bf16.h>

// BailingMoeBlock: T=2048 H=1024 NH=8 NKV=2 HD=128 E=16 TOPK=4 NG=4 TKG=2 F=FS=1024
// Round 7 == Round 6 with the one UB fixed: the 64KB flash LDS buffer is now a
// float4 array (16B-aligned) instead of an unaligned char array that was
// accessed via ds_read_b128/ds_write_b128 and as a global_load_lds destination
// (misaligned b128 LDS ops are a HW fault -> container death).
// Round 6 design recap (k_flash only; rest identical to round 5):
//  - FBK=128, per-thread 4q x 4k / 4q x 4d tiles (area 16): LDS cyc/FMA 2.25 -> ~1.2
//  - K staged via global_load_lds into [128][128] f32 with 16B-chunk XOR swizzle
//    (phys chunk = glob chunk ^ ((row>>2)&7), source pre-swizzled)
//  - Q and V read straight from global (L1/L2-resident), zero LDS cost
//  - P exchanged via 16KB swizzled Ps aliased onto dead K rows 96..127
//  - LDS block 64KB -> 2 blocks/CU with margin

#define T_TOK 2048
#define H_DIM 1024
#define NHEAD 8
#define NKVH 2
#define HDIM 128
#define QKV_DIM 1536
#define E_EXP 16
#define TOPKE 4
#define F_DIM 1024
#define FS_DIM 1024
#define NPAIR (T_TOK*TOPKE)
#define EPS_F 1e-6f

#define DEV __device__ __forceinline__

typedef __attribute__((ext_vector_type(4))) float f32x4;
typedef __attribute__((ext_vector_type(8))) short s16x8;

DEV float us2f(unsigned short u){ return __uint_as_float(((unsigned int)u)<<16); }
DEV unsigned short f2us(float f){
  __hip_bfloat16 b = __float2bfloat16(f);
  unsigned short u; __builtin_memcpy(&u,&b,2); return u;
}

DEV void gl2lds16(const void* g, void* l){
  __builtin_amdgcn_global_load_lds(
      (const __attribute__((address_space(1))) void*)g,
      (__attribute__((address_space(3))) void*)l, 16, 0, 0);
}

// ---- block reductions (256 threads = 4 waves) ----
DEV float bred_sum(float v, float* sm){
  #pragma unroll
  for(int o=32;o>0;o>>=1) v += __shfl_down(v,o);
  int w = threadIdx.x>>6, l = threadIdx.x&63;
  __syncthreads();
  if(l==0) sm[w]=v;
  __syncthreads();
  return sm[0]+sm[1]+sm[2]+sm[3];
}

// ---- weight cvt+transpose: out[z][n][k] = bf16(in[z][k][n]) ----
__global__ __launch_bounds__(256) void k_cvt_t(const float* __restrict__ in,
    unsigned short* __restrict__ out, int Kd, int Nd){
  const int z = blockIdx.z;
  const int kb = blockIdx.y*32, nb = blockIdx.x*32;
  __shared__ float Lt[32][33];
  const int tid = threadIdx.x;
  const int r = tid>>3, c4 = (tid&7)*4;
  const float* src = in + (long long)z*Kd*Nd + (long long)(kb+r)*Nd + nb + c4;
  float4 v = *(const float4*)src;
  Lt[r][c4+0]=v.x; Lt[r][c4+1]=v.y; Lt[r][c4+2]=v.z; Lt[r][c4+3]=v.w;
  __syncthreads();
  ushort4 o;
  o.x = f2us(Lt[c4+0][r]); o.y = f2us(Lt[c4+1][r]);
  o.z = f2us(Lt[c4+2][r]); o.w = f2us(Lt[c4+3][r]);
  *(ushort4*)(out + (long long)z*Nd*Kd + (long long)(nb+r)*Kd + kb + c4) = o;
}

// ---- MFMA GEMM: C[M x N](bf16) = A[M x K](bf16, opt gather) * Bt[N x K]^T ----
// 128x128 tile, BK=32, 256 threads (4 waves, each 64x64 = 4x4 frags).
template<bool GROUPED, bool GATHER>
__global__ __launch_bounds__(256) void gemm_mfma(
    const unsigned short* __restrict__ A, int lda,
    const unsigned short* __restrict__ Bt, int ldbt, long long bstride,
    unsigned short* __restrict__ C, int ldc,
    const int* __restrict__ rowidx, const int* __restrict__ grpoff,
    int Mdense, int K){
  const int z = blockIdx.z;
  const int rb = GROUPED ? grpoff[z] : 0;
  const int re = GROUPED ? grpoff[z+1] : Mdense;
  const int m0 = rb + blockIdx.y*128;
  if(m0 >= re) return;
  const int n0 = blockIdx.x*128;
  const unsigned short* Bz = Bt + (long long)z*bstride;

  __shared__ unsigned short As[128][32];   // [m][k] 8KB
  __shared__ unsigned short Bs[128][32];   // [n][k] 8KB

  const int tid = threadIdx.x;
  const int s0 = tid, s1 = tid+256;
  int gr0 = m0 + (s0>>2), gr1 = m0 + (s1>>2);
  if(GROUPED){ gr0 = min(gr0, re-1); gr1 = min(gr1, re-1); }
  if(GATHER){ gr0 = rowidx[gr0]; gr1 = rowidx[gr1]; }
  const unsigned short* ag0 = A + (long long)gr0*lda + (s0&3)*8;
  const unsigned short* ag1 = A + (long long)gr1*lda + (s1&3)*8;
  const unsigned short* bg0 = Bz + (long long)(n0 + (s0>>2))*ldbt + (s0&3)*8;
  const unsigned short* bg1 = Bz + (long long)(n0 + (s1>>2))*ldbt + (s1&3)*8;
  char* asb = (char*)&As[0][0];
  char* bsb = (char*)&Bs[0][0];
  const int wb = (tid & 192)*16;

  const int w = tid>>6, lane = tid&63;
  const int wm = (w>>1)*64, wn = (w&1)*64;
  const int fr = lane&15, q8 = (lane>>4)*8;

  f32x4 zero = {0.f,0.f,0.f,0.f};
  f32x4 acc[4][4];
  #pragma unroll
  for(int mi=0;mi<4;mi++)
    #pragma unroll
    for(int ni=0;ni<4;ni++) acc[mi][ni]=zero;

  for(int k0=0;k0<K;k0+=32){
    __syncthreads();
    gl2lds16(ag0 + k0, asb + wb);
    gl2lds16(ag1 + k0, asb + 4096 + wb);
    gl2lds16(bg0 + k0, bsb + wb);
    gl2lds16(bg1 + k0, bsb + 4096 + wb);
    __syncthreads();
    s16x8 af[4], bf[4];
    #pragma unroll
    for(int mi=0;mi<4;mi++) af[mi] = *(const s16x8*)&As[wm+mi*16+fr][q8];
    #pragma unroll
    for(int ni=0;ni<4;ni++) bf[ni] = *(const s16x8*)&Bs[wn+ni*16+fr][q8];
    #pragma unroll
    for(int mi=0;mi<4;mi++)
      #pragma unroll
      for(int ni=0;ni<4;ni++)
        acc[mi][ni] = __builtin_amdgcn_mfma_f32_16x16x32_bf16(af[mi], bf[ni], acc[mi][ni], 0,0,0);
  }
  const int q4 = (lane>>4)*4;
  #pragma unroll
  for(int mi=0;mi<4;mi++)
    #pragma unroll
    for(int ni=0;ni<4;ni++){
      const int col = n0 + wn + ni*16 + fr;
      #pragma unroll
      for(int r=0;r<4;r++){
        const int row = m0 + wm + mi*16 + q4 + r;
        if(row < re) C[(long long)row*ldc + col] = f2us(acc[mi][ni][r]);
      }
    }
}

// ---- silu-mul ----
__global__ __launch_bounds__(256) void k_silu(const unsigned short* __restrict__ gu,
    unsigned short* __restrict__ act){
  const int r = blockIdx.x, c = threadIdx.x*4;
  const ushort4 g4 = *(const ushort4*)(gu + (long long)r*2048 + c);
  const ushort4 u4 = *(const ushort4*)(gu + (long long)r*2048 + 1024 + c);
  float g[4] = {us2f(g4.x),us2f(g4.y),us2f(g4.z),us2f(g4.w)};
  float u[4] = {us2f(u4.x),us2f(u4.y),us2f(u4.z),us2f(u4.w)};
  ushort4 o;
  o.x = f2us((g[0]/(1.f+__expf(-g[0])))*u[0]);
  o.y = f2us((g[1]/(1.f+__expf(-g[1])))*u[1]);
  o.z = f2us((g[2]/(1.f+__expf(-g[2])))*u[2]);
  o.w = f2us((g[3]/(1.f+__expf(-g[3])))*u[3]);
  *(ushort4*)(act + (long long)r*1024 + c) = o;
}

// ---- K1: resid = hs + residual ; h = rmsnorm(resid, ln1_w) ----
__global__ __launch_bounds__(256) void k_add_rmsnorm(const float* __restrict__ hs,
    const float* __restrict__ rs, const float* __restrict__ w,
    float* __restrict__ resid, float* __restrict__ h){
  int t = blockIdx.x, tid = threadIdx.x;
  __shared__ float sm[4];
  const long base = (long)t*H_DIM;
  float x[4]; float ss = 0.f;
  #pragma unroll
  for(int i=0;i<4;i++){
    int c = tid + i*256;
    float v = hs[base+c] + rs[base+c];
    x[i]=v; resid[base+c]=v; ss += v*v;
  }
  float tot = bred_sum(ss, sm);
  float rms = rsqrtf(tot/(float)H_DIM + EPS_F);
  #pragma unroll
  for(int i=0;i<4;i++){
    int c = tid + i*256;
    h[base+c] = x[i]*rms*w[c];
  }
}

// ---- fp32 GEMM (QKV + dense only): C = A*B (+D) ----
template<int EPI_ADD>
__global__ __launch_bounds__(256) void gemm_f32(
    const float* __restrict__ A, int lda,
    const float* __restrict__ B, int ldb,
    float* __restrict__ C, int ldc,
    const float* __restrict__ D, int M, int K){
  const int m0 = blockIdx.y*128;
  const int n0 = blockIdx.x*64;
  __shared__ float As[16][132];
  __shared__ float Bs[16][65];
  float acc[8][4];
  #pragma unroll
  for(int i=0;i<8;i++)
    #pragma unroll
    for(int j=0;j<4;j++) acc[i][j]=0.f;
  const int tid = threadIdx.x;
  const int tx = tid & 15, ty = tid >> 4;
  const int ar = tid >> 1, ac = (tid & 1)*8;
  const int brr = tid >> 4, bc = (tid & 15)*4;
  const float* Aptr = A + (long long)(m0+ar)*lda;
  for(int k0=0;k0<K;k0+=16){
    float4 a0 = *(const float4*)(Aptr + k0 + ac);
    float4 a1 = *(const float4*)(Aptr + k0 + ac + 4);
    float4 bv = *(const float4*)(B + (long long)(k0+brr)*ldb + n0 + bc);
    __syncthreads();
    As[ac+0][ar]=a0.x; As[ac+1][ar]=a0.y; As[ac+2][ar]=a0.z; As[ac+3][ar]=a0.w;
    As[ac+4][ar]=a1.x; As[ac+5][ar]=a1.y; As[ac+6][ar]=a1.z; As[ac+7][ar]=a1.w;
    Bs[brr][bc+0]=bv.x; Bs[brr][bc+1]=bv.y; Bs[brr][bc+2]=bv.z; Bs[brr][bc+3]=bv.w;
    __syncthreads();
    #pragma unroll
    for(int kk=0;kk<16;kk++){
      float a[8], b[4];
      #pragma unroll
      for(int i=0;i<8;i++) a[i]=As[kk][ty*8+i];
      #pragma unroll
      for(int j=0;j<4;j++) b[j]=Bs[kk][tx*4+j];
      #pragma unroll
      for(int i=0;i<8;i++)
        #pragma unroll
        for(int j=0;j<4;j++) acc[i][j] = fmaf(a[i], b[j], acc[i][j]);
    }
  }
  #pragma unroll
  for(int i=0;i<8;i++){
    int r = m0 + ty*8 + i;
    float* crow = C + (long long)r*ldc + n0 + tx*4;
    float4 v = make_float4(acc[i][0],acc[i][1],acc[i][2],acc[i][3]);
    if(EPI_ADD){
      const float4 d = *(const float4*)(D + (long long)r*ldc + n0 + tx*4);
      v.x+=d.x; v.y+=d.y; v.z+=d.z; v.w+=d.w;
    }
    *(float4*)crow = v;
  }
}

// ---- K3: per-(t,slot) q/k rmsnorm + rope, v copy. 64 threads. ----
__global__ __launch_bounds__(64) void k_qkv_post(const float* __restrict__ qkv,
    const float* __restrict__ qw, const float* __restrict__ kw,
    const int* __restrict__ pos,
    float* __restrict__ qb, float* __restrict__ kb, float* __restrict__ vb){
  int slot = blockIdx.x, t = blockIdx.y, lane = threadIdx.x;
  const float* x = qkv + (long long)t*QKV_DIM + slot*HDIM;
  float x0 = x[lane], x1 = x[lane+64];
  if(slot < 10){
    float ss = x0*x0 + x1*x1;
    #pragma unroll
    for(int o=32;o>0;o>>=1) ss += __shfl_xor(ss,o);
    float rms = rsqrtf(ss/(float)HDIM + EPS_F);
    const float* w = (slot<8)? qw : kw;
    float n0 = x0*rms*w[lane];
    float n1 = x1*rms*w[lane+64];
    float p = (float)pos[t];
    float invf = __expf(-((float)lane/64.f)*9.210340371976184f);
    float ang = p*invf;
    float s = sinf(ang), c = cosf(ang);
    float o0 = n0*c - n1*s;
    float o1 = n1*c + n0*s;
    float* dst = (slot<8)? (qb + ((long long)slot*T_TOK + t)*HDIM)
                         : (kb + ((long long)(slot-8)*T_TOK + t)*HDIM);
    dst[lane]=o0; dst[lane+64]=o1;
  } else {
    float* dst = vb + ((long long)(slot-10)*T_TOK + t)*HDIM;
    dst[lane]=x0; dst[lane+64]=x1;
  }
}

// ---- K4: flash attention (fp32), round-6/7 structure ----
// 512 blocks: grid (8 heads, 64 qtiles of 32 rows), complementary dispatch
// order. Per-thread 4q x 4k (QK) and 4q x 4d (PV) tiles. K in 64KB LDS via
// swizzled global_load_lds; Q/V from global; P via 16KB Ps aliased onto dead
// K rows 96..127. LDS = 64KB (float4 array, 16B-aligned) -> 2 blocks/CU.
#define FBQ 32
#define FBK 128
__global__ __launch_bounds__(256,2) void k_flash(const float* __restrict__ qb,
    const float* __restrict__ kb, const float* __restrict__ vb,
    float* __restrict__ ctx){
  const int h = blockIdx.x;
  const int by = blockIdx.y;
  const int qt = (by < 32) ? (63 - by) : (by - 32);
  const int kv = h >> 2;
  const int q0 = qt * FBQ;
  const int tid = threadIdx.x;
  const int lane = tid & 63;
  const int w = tid >> 6;
  const int tx = tid & 31;        // k-group (QK) / d-group (PV)
  const int ty = tid >> 5;        // q-group: rows q0 + ty*4 + qi
  const int fsw = tx & 7;         // chunk-swizzle term for this thread's K rows

  __shared__ float4 smem4[4096];             // 64KB, 16B-aligned
  char*  smem = (char*)smem4;
  float* Ksf  = (float*)smem;                // [128][128] f32, 16B-chunk swizzled
  float* Psf  = (float*)(smem + 49152);      // [128][32] f32, swizzled (aliases K rows 96..127)

  const float scale = 0.08838834764831845f;
  const float* kbase = kb + (long long)kv*T_TOK*HDIM;
  const float* vbase = vb + (long long)kv*T_TOK*HDIM;
  const float* qrow0 = qb + ((long long)h*T_TOK + q0 + ty*4)*HDIM;

  float m_[4], l_[4], O[4][4];
  #pragma unroll
  for(int qi=0;qi<4;qi++){
    m_[qi] = -1e30f; l_[qi] = 0.f;
    #pragma unroll
    for(int j=0;j<4;j++) O[qi][j] = 0.f;
  }

  const int nkt = (qt >> 2) + 1;

  for(int kt=0; kt<nkt; kt++){
    const int k0 = kt * FBK;
    __syncthreads();                          // B1: prior PV readers of Ps done
    {
      // stage K[k0 .. k0+127][0..127] -> Ksf, 16 x 1KB DMA per wave.
      // lds chunk c holds global chunk c ^ f(row), f = (row>>2)&7 (involution);
      // per-inst rows (rbase, rbase+1) share row>>2, so f is inst-uniform.
      const float* kcur = kbase + (long long)k0*HDIM;
      #pragma unroll
      for(int i=0;i<16;i++){
        const int rbase = (w<<5) + (i<<1);
        const int f = (i>>1) & 7;             // ((w*32+2i)>>2)&7 == (i>>1)&7
        const float* src = kcur + (long long)(rbase + (lane>>5))*HDIM
                                + (((lane&31)^f)<<2);
        gl2lds16(src, smem + rbase*512);
      }
    }
    __syncthreads();                          // B2: staged (vmcnt drained by barrier)

    // ---- QK: s[qi][ki] over d, K from swizzled LDS, Q from global ----
    float s[4][4];
    #pragma unroll
    for(int qi=0;qi<4;qi++)
      #pragma unroll
      for(int ki=0;ki<4;ki++) s[qi][ki] = 0.f;

    #pragma unroll 2
    for(int dc=0; dc<32; dc++){
      float4 qv[4];
      #pragma unroll
      for(int qi=0;qi<4;qi++) qv[qi] = *(const float4*)(qrow0 + qi*HDIM + dc*4);
      float4 kf[4];
      #pragma unroll
      for(int ki=0;ki<4;ki++)
        kf[ki] = *(const float4*)&Ksf[(size_t)(4*tx+ki)*128 + ((dc ^ fsw)<<2)];
      #pragma unroll
      for(int qi=0;qi<4;qi++)
        #pragma unroll
        for(int ki=0;ki<4;ki++){
          s[qi][ki] = fmaf(qv[qi].x, kf[ki].x, s[qi][ki]);
          s[qi][ki] = fmaf(qv[qi].y, kf[ki].y, s[qi][ki]);
          s[qi][ki] = fmaf(qv[qi].z, kf[ki].z, s[qi][ki]);
          s[qi][ki] = fmaf(qv[qi].w, kf[ki].w, s[qi][ki]);
        }
    }

    // ---- scale + causal mask + online softmax (stats thread-local) ----
    const bool last = (kt == nkt-1);
    float rm[4];
    #pragma unroll
    for(int qi=0;qi<4;qi++){
      #pragma unroll
      for(int ki=0;ki<4;ki++){
        float v = s[qi][ki]*scale;
        if(last && (k0 + 4*tx + ki > q0 + ty*4 + qi)) v = -1e30f;
        s[qi][ki] = v;
      }
      rm[qi] = fmaxf(fmaxf(s[qi][0],s[qi][1]), fmaxf(s[qi][2],s[qi][3]));
    }
    #pragma unroll
    for(int o=1;o<32;o<<=1){
      #pragma unroll
      for(int qi=0;qi<4;qi++) rm[qi] = fmaxf(rm[qi], __shfl_xor(rm[qi], o));
    }
    float a_[4], rs[4];
    #pragma unroll
    for(int qi=0;qi<4;qi++){
      float mn = fmaxf(m_[qi], rm[qi]);
      a_[qi] = __expf(m_[qi] - mn);
      m_[qi] = mn;
      float r = 0.f;
      #pragma unroll
      for(int ki=0;ki<4;ki++){ s[qi][ki] = __expf(s[qi][ki] - mn); r += s[qi][ki]; }
      rs[qi] = r;
    }
    #pragma unroll
    for(int o=1;o<32;o<<=1){
      #pragma unroll
      for(int qi=0;qi<4;qi++) rs[qi] += __shfl_xor(rs[qi], o);
    }
    #pragma unroll
    for(int qi=0;qi<4;qi++){
      l_[qi] = l_[qi]*a_[qi] + rs[qi];
      #pragma unroll
      for(int j=0;j<4;j++) O[qi][j] *= a_[qi];
    }

    __syncthreads();                          // B3: all QK reads of K done -> Ps may clobber
    // Ps[k][q] store, chunk swizzled: phys chunk = ty ^ ((k>>2)&7) = ty ^ fsw
    #pragma unroll
    for(int ki=0;ki<4;ki++){
      float4 pv;
      pv.x = s[0][ki]; pv.y = s[1][ki]; pv.z = s[2][ki]; pv.w = s[3][ki];
      *(float4*)&Psf[(size_t)(4*tx+ki)*32 + ((ty ^ fsw)<<2)] = pv;
    }
    __syncthreads();                          // B4: Ps visible

    // ---- PV: O[qi][j] += P[q][k]*V[k][d], V from global, P from LDS ----
    const float* vcur = vbase + (long long)k0*HDIM + tx*4;
    #pragma unroll 4
    for(int k=0;k<FBK;k++){
      float4 p4 = *(const float4*)&Psf[(size_t)k*32 + ((ty ^ ((k>>2)&7))<<2)];
      float4 vv = *(const float4*)(vcur + (size_t)k*HDIM);
      O[0][0]=fmaf(p4.x,vv.x,O[0][0]); O[0][1]=fmaf(p4.x,vv.y,O[0][1]);
      O[0][2]=fmaf(p4.x,vv.z,O[0][2]); O[0][3]=fmaf(p4.x,vv.w,O[0][3]);
      O[1][0]=fmaf(p4.y,vv.x,O[1][0]); O[1][1]=fmaf(p4.y,vv.y,O[1][1]);
      O[1][2]=fmaf(p4.y,vv.z,O[1][2]); O[1][3]=fmaf(p4.y,vv.w,O[1][3]);
      O[2][0]=fmaf(p4.z,vv.x,O[2][0]); O[2][1]=fmaf(p4.z,vv.y,O[2][1]);
      O[2][2]=fmaf(p4.z,vv.z,O[2][2]); O[2][3]=fmaf(p4.z,vv.w,O[2][3]);
      O[3][0]=fmaf(p4.w,vv.x,O[3][0]); O[3][1]=fmaf(p4.w,vv.y,O[3][1]);
      O[3][2]=fmaf(p4.w,vv.z,O[3][2]); O[3][3]=fmaf(p4.w,vv.w,O[3][3]);
    }
  }

  #pragma unroll
  for(int qi=0;qi<4;qi++){
    float inv = 1.f/l_[qi];
    float4 o4 = make_float4(O[qi][0]*inv, O[qi][1]*inv, O[qi][2]*inv, O[qi][3]*inv);
    *(float4*)(ctx + (long long)(q0 + ty*4 + qi)*(NHEAD*HDIM) + h*HDIM + tx*4) = o4;
  }
}

// ---- K6: read resid2 (=out1), write h2f (fp32, router) + h2b (bf16, GEMM A) ----
__global__ __launch_bounds__(256) void k_rms2(const float* __restrict__ r2,
    const float* __restrict__ w, float* __restrict__ h2f,
    unsigned short* __restrict__ h2b){
  int t = blockIdx.x, tid = threadIdx.x;
  __shared__ float sm[4];
  const long base = (long)t*H_DIM;
  float x[4]; float ss=0.f;
  #pragma unroll
  for(int i=0;i<4;i++){
    int c = tid+i*256;
    float v = r2[base+c];
    x[i]=v; ss += v*v;
  }
  float tot = bred_sum(ss, sm);
  float rms = rsqrtf(tot/(float)H_DIM + EPS_F);
  #pragma unroll
  for(int i=0;i<4;i++){
    int c = tid+i*256;
    float v = x[i]*rms*w[c];
    h2f[base+c] = v;
    h2b[base+c] = f2us(v);
  }
}

// ---- K7: router (fp32 exact) ----
__global__ __launch_bounds__(256) void k_router(const float* __restrict__ h2,
    const float* __restrict__ gw, const float* __restrict__ eb,
    int* __restrict__ topk_idx, float* __restrict__ topk_w, int* __restrict__ counts){
  int t = blockIdx.x, tid = threadIdx.x;
  int e = tid & 15, seg = tid >> 4;
  const float* hrow = h2 + (long long)t*H_DIM;
  float part = 0.f;
  #pragma unroll 4
  for(int i=0;i<64;i++){
    int hh = seg*64 + i;
    part += hrow[hh]*gw[hh*E_EXP + e];
  }
  __shared__ float pm[16][17];
  __shared__ float sS[16], sfc[16];
  pm[seg][e] = part;
  __syncthreads();
  if(tid < 16){
    float l = 0.f;
    #pragma unroll
    for(int s=0;s<16;s++) l += pm[s][tid];
    float sg = 1.f/(1.f+expf(-l));
    sS[tid]=sg; sfc[tid]=sg+eb[tid];
  }
  __syncthreads();
  if(tid==0){
    float gs[4];
    #pragma unroll
    for(int g=0; g<4; g++){
      float m1=-1e30f, m2=-1e30f;
      for(int j=0;j<4;j++){
        float v=sfc[g*4+j];
        if(v>m1){ m2=m1; m1=v; } else if(v>m2){ m2=v; }
      }
      gs[g]=m1+m2;
    }
    int g1=0; for(int g=1;g<4;g++) if(gs[g]>gs[g1]) g1=g;
    int g2=-1; for(int g=0;g<4;g++){ if(g==g1) continue; if(g2<0||gs[g]>gs[g2]) g2=g; }
    bool taken[16];
    #pragma unroll
    for(int i=0;i<16;i++) taken[i]=false;
    int idx[4];
    for(int j=0;j<4;j++){
      int best=-1; float bv=-1e30f;
      for(int i=0;i<16;i++){
        int g=i>>2;
        if(g!=g1 && g!=g2) continue;
        if(taken[i]) continue;
        if(best<0 || sfc[i]>bv){ best=i; bv=sfc[i]; }
      }
      taken[best]=true; idx[j]=best;
    }
    float w[4]; float s=0.f;
    #pragma unroll
    for(int j=0;j<4;j++){ w[j]=sS[idx[j]]; s+=w[j]; }
    s += 1e-20f;
    #pragma unroll
    for(int j=0;j<4;j++){
      topk_idx[t*4+j]=idx[j];
      topk_w[t*4+j]=w[j]/s;
      atomicAdd(&counts[idx[j]],1);
    }
  }
}

__global__ void k_zero(int* __restrict__ counts){ if(threadIdx.x<16) counts[threadIdx.x]=0; }

__global__ void k_scan(const int* __restrict__ counts, int* __restrict__ offs, int* __restrict__ cursor){
  if(threadIdx.x==0){
    int s=0;
    for(int e2=0;e2<16;e2++){ offs[e2]=s; cursor[e2]=s; s+=counts[e2]; }
    offs[16]=s;
  }
}

__global__ __launch_bounds__(256) void k_scatter(const int* __restrict__ topk_idx,
    int* __restrict__ cursor, int* __restrict__ pair_tok, int* __restrict__ tok2pair){
  int i = blockIdx.x*256 + threadIdx.x;
  int e = topk_idx[i];
  int pos = atomicAdd(&cursor[e],1);
  pair_tok[pos] = i>>2;
  tok2pair[i] = pos;
}

// ---- K15: out0 = sum_j 2*w_j*y[pair_j] + shared (bf16 in, fp32 out) ----
__global__ __launch_bounds__(256) void k_combine(const unsigned short* __restrict__ y,
    const unsigned short* __restrict__ sout, const int* __restrict__ tok2pair,
    const float* __restrict__ topk_w, float* __restrict__ out0){
  int t = blockIdx.x, tid = threadIdx.x;
  int p[4]; float w[4];
  #pragma unroll
  for(int j=0;j<4;j++){ p[j]=tok2pair[t*4+j]; w[j]=topk_w[t*4+j]*2.0f; }
  const long base = (long)t*H_DIM;
  #pragma unroll
  for(int i=0;i<4;i++){
    int c = tid + i*256;
    float v = us2f(sout[base+c]);
    #pragma unroll
    for(int j=0;j<4;j++) v += w[j]*us2f(y[(long long)p[j]*H_DIM + c]);
    out0[base+c] = v;
  }
}

extern "C" void kernel_launch(void* const* d_in, const int* in_sizes, int n_in,
                              void* d_out, int out_size, void* d_ws, size_t ws_size,
                              hipStream_t stream) {
  const float* hs   = (const float*)d_in[0];
  const float* rsd  = (const float*)d_in[1];
  const int*   pos  = (const int*)d_in[2];
  const float* ln1  = (const float*)d_in[3];
  const float* qkvw = (const float*)d_in[4];
  const float* qnw  = (const float*)d_in[5];
  const float* knw  = (const float*)d_in[6];
  const float* dw   = (const float*)d_in[7];
  const float* ln2  = (const float*)d_in[8];
  const float* gw   = (const float*)d_in[9];
  const float* eb   = (const float*)d_in[10];
  const float* w13  = (const float*)d_in[11];
  const float* w2   = (const float*)d_in[12];
  const float* wsgu = (const float*)d_in[13];
  const float* wsd  = (const float*)d_in[14];
  float* out0 = (float*)d_out;
  float* out1 = out0 + (size_t)T_TOK*H_DIM;   // resid2

  char* W = (char*)d_ws;
  float* resid = (float*)(W + 0);
  float* h     = (float*)(W + 8388608);
  float* ctx   = h;
  float* qkv   = (float*)(W + 16777216);
  float* qb    = (float*)(W + 29360128);
  float* h2f   = (float*)(W + 37748736);
  float* kb    = (float*)(W + 46137344);
  float* vb    = (float*)(W + 48234496);
  unsigned short* gu    = (unsigned short*)(W + 8388608);
  unsigned short* ybuf  = (unsigned short*)(W + 8388608);
  unsigned short* sgu   = (unsigned short*)(W + 16777216);
  unsigned short* sact  = (unsigned short*)(W + 0);
  unsigned short* sout  = (unsigned short*)(W + 46137344);
  unsigned short* h2b   = (unsigned short*)(W + 50331648);
  unsigned short* act   = (unsigned short*)(W + 54525952);
  unsigned short* w13t  = (unsigned short*)(W + 71303168);
  unsigned short* w2t   = (unsigned short*)(W + 138412032);
  unsigned short* wsgut = (unsigned short*)(W + 171966464);
  unsigned short* wsdt  = (unsigned short*)(W + 176160768);
  float* topkw = (float*)(W + 178257920);
  int* topki   = (int*)(W + 178290688);
  int* ptok    = (int*)(W + 178323456);
  int* t2p     = (int*)(W + 178356224);
  int* cnt     = (int*)(W + 178388992);
  int* offs    = (int*)(W + 178389056);
  int* cur     = (int*)(W + 178389184);

  // 0. weight cvt + transpose -> bf16 B^T
  k_cvt_t<<<dim3(64,32,16), 256, 0, stream>>>(w13,  w13t,  1024, 2048);
  k_cvt_t<<<dim3(32,32,16), 256, 0, stream>>>(w2,   w2t,   1024, 1024);
  k_cvt_t<<<dim3(64,32,1),  256, 0, stream>>>(wsgu, wsgut, 1024, 2048);
  k_cvt_t<<<dim3(32,32,1),  256, 0, stream>>>(wsd,  wsdt,  1024, 1024);
  // A. resid + rmsnorm
  k_add_rmsnorm<<<T_TOK, 256, 0, stream>>>(hs, rsd, ln1, resid, h);
  // B. qkv = h @ qkv_w (fp32)
  gemm_f32<0><<<dim3(QKV_DIM/64, T_TOK/128), 256, 0, stream>>>(
      h, H_DIM, qkvw, QKV_DIM, qkv, QKV_DIM, nullptr, T_TOK, H_DIM);
  // C. q/k norm + rope
  k_qkv_post<<<dim3(12, T_TOK), 64, 0, stream>>>(qkv, qnw, knw, pos, qb, kb, vb);
  // D. flash attention (512 blocks, complementary order)
  k_flash<<<dim3(NHEAD, 64), 256, 0, stream>>>(qb, kb, vb, ctx);
  // E. resid2 = ctx @ dense_w + resid -> out1 (fp32)
  gemm_f32<1><<<dim3(H_DIM/64, T_TOK/128), 256, 0, stream>>>(
      ctx, NHEAD*HDIM, dw, H_DIM, out1, H_DIM, resid, T_TOK, NHEAD*HDIM);
  // F. h2 = rmsnorm(out1)
  k_rms2<<<T_TOK, 256, 0, stream>>>(out1, ln2, h2f, h2b);
  // G. router
  k_zero<<<1, 64, 0, stream>>>(cnt);
  k_router<<<T_TOK, 256, 0, stream>>>(h2f, gw, eb, topki, topkw, cnt);
  k_scan<<<1, 64, 0, stream>>>(cnt, offs, cur);
  k_scatter<<<NPAIR/256, 256, 0, stream>>>(topki, cur, ptok, t2p);
  // H. shared expert (MFMA)
  gemm_mfma<false,false><<<dim3(16,16,1), 256, 0, stream>>>(
      h2b, 1024, wsgut, 1024, 0, sgu, 2048, nullptr, nullptr, T_TOK, 1024);
  k_silu<<<T_TOK, 256, 0, stream>>>(sgu, sact);
  gemm_mfma<false,false><<<dim3(8,16,1), 256, 0, stream>>>(
      sact, 1024, wsdt, 1024, 0, sout, 1024, nullptr, nullptr, T_TOK, 1024);
  // I. MoE expert FFN (MFMA, grouped)
  gemm_mfma<true,true><<<dim3(16,64,16), 256, 0, stream>>>(
      h2b, 1024, w13t, 1024, (long long)2048*1024, gu, 2048, ptok, offs, 0, 1024);
  k_silu<<<NPAIR, 256, 0, stream>>>(gu, act);
  gemm_mfma<true,false><<<dim3(8,64,16), 256, 0, stream>>>(
      act, 1024, w2t, 1024, (long long)1024*1024, ybuf, 1024, nullptr, offs, 0, 1024);
  // K. combine -> out0
  k_combine<<<T_TOK, 256, 0, stream>>>(ybuf, sout, t2p, topkw, out0);
}

// Round 4
// 1087.781 us; speedup vs baseline: 1.0298x; 1.0298x over previous
//
#include <hip/hip_runtime.h>
#include <hip/hip_bf16.h>

// BailingMoeBlock: T=2048 H=1024 NH=8 NKV=2 HD=128 E=16 TOPK=4 NG=4 TKG=2 F=FS=1024
// Round 8: fix k_flash MAKESPAN (round-7 lesson: with 2 co-resident blocks,
// CU time = max(a,b), not avg; pair (16,1) CU ran 16 units vs 8.5 avg ->
// occupancy 13% exactly matches (16+1)/(2*16)).
//  - Split heavy q-tiles (qt>=32, nkt 9..16) into lo/hi K-halves (4..8 units),
//    partials (O,m,l) -> 8MB scratch aliased on dead qkv region; exact fp32
//    merge kernel (k_fmerge, 1 wave/row). Light rows (qt<32) unchanged,
//    written directly. 768 work items <= 8 units, heaviest dispatched first.
//  - k_flash core (LDS layout, swizzle, QK/PV tiles) identical to round 7.
// Everything else identical to round 7.

#define T_TOK 2048
#define H_DIM 1024
#define NHEAD 8
#define NKVH 2
#define HDIM 128
#define QKV_DIM 1536
#define E_EXP 16
#define TOPKE 4
#define F_DIM 1024
#define FS_DIM 1024
#define NPAIR (T_TOK*TOPKE)
#define EPS_F 1e-6f

#define DEV __device__ __forceinline__

typedef __attribute__((ext_vector_type(4))) float f32x4;
typedef __attribute__((ext_vector_type(8))) short s16x8;

DEV float us2f(unsigned short u){ return __uint_as_float(((unsigned int)u)<<16); }
DEV unsigned short f2us(float f){
  __hip_bfloat16 b = __float2bfloat16(f);
  unsigned short u; __builtin_memcpy(&u,&b,2); return u;
}

DEV void gl2lds16(const void* g, void* l){
  __builtin_amdgcn_global_load_lds(
      (const __attribute__((address_space(1))) void*)g,
      (__attribute__((address_space(3))) void*)l, 16, 0, 0);
}

// ---- block reductions (256 threads = 4 waves) ----
DEV float bred_sum(float v, float* sm){
  #pragma unroll
  for(int o=32;o>0;o>>=1) v += __shfl_down(v,o);
  int w = threadIdx.x>>6, l = threadIdx.x&63;
  __syncthreads();
  if(l==0) sm[w]=v;
  __syncthreads();
  return sm[0]+sm[1]+sm[2]+sm[3];
}

// ---- weight cvt+transpose: out[z][n][k] = bf16(in[z][k][n]) ----
__global__ __launch_bounds__(256) void k_cvt_t(const float* __restrict__ in,
    unsigned short* __restrict__ out, int Kd, int Nd){
  const int z = blockIdx.z;
  const int kb = blockIdx.y*32, nb = blockIdx.x*32;
  __shared__ float Lt[32][33];
  const int tid = threadIdx.x;
  const int r = tid>>3, c4 = (tid&7)*4;
  const float* src = in + (long long)z*Kd*Nd + (long long)(kb+r)*Nd + nb + c4;
  float4 v = *(const float4*)src;
  Lt[r][c4+0]=v.x; Lt[r][c4+1]=v.y; Lt[r][c4+2]=v.z; Lt[r][c4+3]=v.w;
  __syncthreads();
  ushort4 o;
  o.x = f2us(Lt[c4+0][r]); o.y = f2us(Lt[c4+1][r]);
  o.z = f2us(Lt[c4+2][r]); o.w = f2us(Lt[c4+3][r]);
  *(ushort4*)(out + (long long)z*Nd*Kd + (long long)(nb+r)*Kd + kb + c4) = o;
}

// ---- MFMA GEMM: C[M x N](bf16) = A[M x K](bf16, opt gather) * Bt[N x K]^T ----
template<bool GROUPED, bool GATHER>
__global__ __launch_bounds__(256) void gemm_mfma(
    const unsigned short* __restrict__ A, int lda,
    const unsigned short* __restrict__ Bt, int ldbt, long long bstride,
    unsigned short* __restrict__ C, int ldc,
    const int* __restrict__ rowidx, const int* __restrict__ grpoff,
    int Mdense, int K){
  const int z = blockIdx.z;
  const int rb = GROUPED ? grpoff[z] : 0;
  const int re = GROUPED ? grpoff[z+1] : Mdense;
  const int m0 = rb + blockIdx.y*128;
  if(m0 >= re) return;
  const int n0 = blockIdx.x*128;
  const unsigned short* Bz = Bt + (long long)z*bstride;

  __shared__ unsigned short As[128][32];   // [m][k] 8KB
  __shared__ unsigned short Bs[128][32];   // [n][k] 8KB

  const int tid = threadIdx.x;
  const int s0 = tid, s1 = tid+256;
  int gr0 = m0 + (s0>>2), gr1 = m0 + (s1>>2);
  if(GROUPED){ gr0 = min(gr0, re-1); gr1 = min(gr1, re-1); }
  if(GATHER){ gr0 = rowidx[gr0]; gr1 = rowidx[gr1]; }
  const unsigned short* ag0 = A + (long long)gr0*lda + (s0&3)*8;
  const unsigned short* ag1 = A + (long long)gr1*lda + (s1&3)*8;
  const unsigned short* bg0 = Bz + (long long)(n0 + (s0>>2))*ldbt + (s0&3)*8;
  const unsigned short* bg1 = Bz + (long long)(n0 + (s1>>2))*ldbt + (s1&3)*8;
  char* asb = (char*)&As[0][0];
  char* bsb = (char*)&Bs[0][0];
  const int wb = (tid & 192)*16;

  const int w = tid>>6, lane = tid&63;
  const int wm = (w>>1)*64, wn = (w&1)*64;
  const int fr = lane&15, q8 = (lane>>4)*8;

  f32x4 zero = {0.f,0.f,0.f,0.f};
  f32x4 acc[4][4];
  #pragma unroll
  for(int mi=0;mi<4;mi++)
    #pragma unroll
    for(int ni=0;ni<4;ni++) acc[mi][ni]=zero;

  for(int k0=0;k0<K;k0+=32){
    __syncthreads();
    gl2lds16(ag0 + k0, asb + wb);
    gl2lds16(ag1 + k0, asb + 4096 + wb);
    gl2lds16(bg0 + k0, bsb + wb);
    gl2lds16(bg1 + k0, bsb + 4096 + wb);
    __syncthreads();
    s16x8 af[4], bf[4];
    #pragma unroll
    for(int mi=0;mi<4;mi++) af[mi] = *(const s16x8*)&As[wm+mi*16+fr][q8];
    #pragma unroll
    for(int ni=0;ni<4;ni++) bf[ni] = *(const s16x8*)&Bs[wn+ni*16+fr][q8];
    #pragma unroll
    for(int mi=0;mi<4;mi++)
      #pragma unroll
      for(int ni=0;ni<4;ni++)
        acc[mi][ni] = __builtin_amdgcn_mfma_f32_16x16x32_bf16(af[mi], bf[ni], acc[mi][ni], 0,0,0);
  }
  const int q4 = (lane>>4)*4;
  #pragma unroll
  for(int mi=0;mi<4;mi++)
    #pragma unroll
    for(int ni=0;ni<4;ni++){
      const int col = n0 + wn + ni*16 + fr;
      #pragma unroll
      for(int r=0;r<4;r++){
        const int row = m0 + wm + mi*16 + q4 + r;
        if(row < re) C[(long long)row*ldc + col] = f2us(acc[mi][ni][r]);
      }
    }
}

// ---- silu-mul ----
__global__ __launch_bounds__(256) void k_silu(const unsigned short* __restrict__ gu,
    unsigned short* __restrict__ act){
  const int r = blockIdx.x, c = threadIdx.x*4;
  const ushort4 g4 = *(const ushort4*)(gu + (long long)r*2048 + c);
  const ushort4 u4 = *(const ushort4*)(gu + (long long)r*2048 + 1024 + c);
  float g[4] = {us2f(g4.x),us2f(g4.y),us2f(g4.z),us2f(g4.w)};
  float u[4] = {us2f(u4.x),us2f(u4.y),us2f(u4.z),us2f(u4.w)};
  ushort4 o;
  o.x = f2us((g[0]/(1.f+__expf(-g[0])))*u[0]);
  o.y = f2us((g[1]/(1.f+__expf(-g[1])))*u[1]);
  o.z = f2us((g[2]/(1.f+__expf(-g[2])))*u[2]);
  o.w = f2us((g[3]/(1.f+__expf(-g[3])))*u[3]);
  *(ushort4*)(act + (long long)r*1024 + c) = o;
}

// ---- K1: resid = hs + residual ; h = rmsnorm(resid, ln1_w) ----
__global__ __launch_bounds__(256) void k_add_rmsnorm(const float* __restrict__ hs,
    const float* __restrict__ rs, const float* __restrict__ w,
    float* __restrict__ resid, float* __restrict__ h){
  int t = blockIdx.x, tid = threadIdx.x;
  __shared__ float sm[4];
  const long base = (long)t*H_DIM;
  float x[4]; float ss = 0.f;
  #pragma unroll
  for(int i=0;i<4;i++){
    int c = tid + i*256;
    float v = hs[base+c] + rs[base+c];
    x[i]=v; resid[base+c]=v; ss += v*v;
  }
  float tot = bred_sum(ss, sm);
  float rms = rsqrtf(tot/(float)H_DIM + EPS_F);
  #pragma unroll
  for(int i=0;i<4;i++){
    int c = tid + i*256;
    h[base+c] = x[i]*rms*w[c];
  }
}

// ---- fp32 GEMM (QKV + dense only): C = A*B (+D) ----
template<int EPI_ADD>
__global__ __launch_bounds__(256) void gemm_f32(
    const float* __restrict__ A, int lda,
    const float* __restrict__ B, int ldb,
    float* __restrict__ C, int ldc,
    const float* __restrict__ D, int M, int K){
  const int m0 = blockIdx.y*128;
  const int n0 = blockIdx.x*64;
  __shared__ float As[16][132];
  __shared__ float Bs[16][65];
  float acc[8][4];
  #pragma unroll
  for(int i=0;i<8;i++)
    #pragma unroll
    for(int j=0;j<4;j++) acc[i][j]=0.f;
  const int tid = threadIdx.x;
  const int tx = tid & 15, ty = tid >> 4;
  const int ar = tid >> 1, ac = (tid & 1)*8;
  const int brr = tid >> 4, bc = (tid & 15)*4;
  const float* Aptr = A + (long long)(m0+ar)*lda;
  for(int k0=0;k0<K;k0+=16){
    float4 a0 = *(const float4*)(Aptr + k0 + ac);
    float4 a1 = *(const float4*)(Aptr + k0 + ac + 4);
    float4 bv = *(const float4*)(B + (long long)(k0+brr)*ldb + n0 + bc);
    __syncthreads();
    As[ac+0][ar]=a0.x; As[ac+1][ar]=a0.y; As[ac+2][ar]=a0.z; As[ac+3][ar]=a0.w;
    As[ac+4][ar]=a1.x; As[ac+5][ar]=a1.y; As[ac+6][ar]=a1.z; As[ac+7][ar]=a1.w;
    Bs[brr][bc+0]=bv.x; Bs[brr][bc+1]=bv.y; Bs[brr][bc+2]=bv.z; Bs[brr][bc+3]=bv.w;
    __syncthreads();
    #pragma unroll
    for(int kk=0;kk<16;kk++){
      float a[8], b[4];
      #pragma unroll
      for(int i=0;i<8;i++) a[i]=As[kk][ty*8+i];
      #pragma unroll
      for(int j=0;j<4;j++) b[j]=Bs[kk][tx*4+j];
      #pragma unroll
      for(int i=0;i<8;i++)
        #pragma unroll
        for(int j=0;j<4;j++) acc[i][j] = fmaf(a[i], b[j], acc[i][j]);
    }
  }
  #pragma unroll
  for(int i=0;i<8;i++){
    int r = m0 + ty*8 + i;
    float* crow = C + (long long)r*ldc + n0 + tx*4;
    float4 v = make_float4(acc[i][0],acc[i][1],acc[i][2],acc[i][3]);
    if(EPI_ADD){
      const float4 d = *(const float4*)(D + (long long)r*ldc + n0 + tx*4);
      v.x+=d.x; v.y+=d.y; v.z+=d.z; v.w+=d.w;
    }
    *(float4*)crow = v;
  }
}

// ---- K3: per-(t,slot) q/k rmsnorm + rope, v copy. 64 threads. ----
__global__ __launch_bounds__(64) void k_qkv_post(const float* __restrict__ qkv,
    const float* __restrict__ qw, const float* __restrict__ kw,
    const int* __restrict__ pos,
    float* __restrict__ qb, float* __restrict__ kb, float* __restrict__ vb){
  int slot = blockIdx.x, t = blockIdx.y, lane = threadIdx.x;
  const float* x = qkv + (long long)t*QKV_DIM + slot*HDIM;
  float x0 = x[lane], x1 = x[lane+64];
  if(slot < 10){
    float ss = x0*x0 + x1*x1;
    #pragma unroll
    for(int o=32;o>0;o>>=1) ss += __shfl_xor(ss,o);
    float rms = rsqrtf(ss/(float)HDIM + EPS_F);
    const float* w = (slot<8)? qw : kw;
    float n0 = x0*rms*w[lane];
    float n1 = x1*rms*w[lane+64];
    float p = (float)pos[t];
    float invf = __expf(-((float)lane/64.f)*9.210340371976184f);
    float ang = p*invf;
    float s = sinf(ang), c = cosf(ang);
    float o0 = n0*c - n1*s;
    float o1 = n1*c + n0*s;
    float* dst = (slot<8)? (qb + ((long long)slot*T_TOK + t)*HDIM)
                         : (kb + ((long long)(slot-8)*T_TOK + t)*HDIM);
    dst[lane]=o0; dst[lane+64]=o1;
  } else {
    float* dst = vb + ((long long)(slot-10)*T_TOK + t)*HDIM;
    dst[lane]=x0; dst[lane+64]=x1;
  }
}

// ---- K4: flash attention (fp32), round-8 structure ----
// grid (8 heads, 96 items). Items (heaviest dispatched first):
//   by in [0,64): heavy half: qt = 63-(by>>1) in [32,63], nkt = (qt>>2)+1 (9..16),
//                 h1 = nkt>>1; by&1==1 -> lo chunk [0,h1), ==0 -> hi chunk [h1,nkt).
//                 Writes UNNORMALIZED partial O + (m,l) to Opart/Mpart, slot by&1.
//   by in [64,96): light full row qt = 95-by in [0,31], direct normalized ctx write.
// Core (LDS layout, swizzle, 4qx4k / 4qx4d tiles) identical to round 7.
#define FBQ 32
#define FBK 128
__global__ __launch_bounds__(256,2) void k_flash(const float* __restrict__ qb,
    const float* __restrict__ kb, const float* __restrict__ vb,
    float* __restrict__ ctx, float* __restrict__ Opart, float* __restrict__ Mpart){
  const int h = blockIdx.x;
  const int by = blockIdx.y;
  int qt, c0, c1, nktf, pc;
  bool heavy;
  if(by < 64){
    heavy = true;
    qt = 63 - (by>>1);
    nktf = (qt>>2) + 1;
    const int h1 = nktf>>1;
    pc = by & 1;
    if(pc){ c0 = 0; c1 = h1; } else { c0 = h1; c1 = nktf; }
  } else {
    heavy = false;
    qt = 95 - by;
    nktf = (qt>>2) + 1;
    c0 = 0; c1 = nktf; pc = 0;
  }
  const int kv = h >> 2;
  const int q0 = qt * FBQ;
  const int tid = threadIdx.x;
  const int lane = tid & 63;
  const int w = tid >> 6;
  const int tx = tid & 31;        // k-group (QK) / d-group (PV)
  const int ty = tid >> 5;        // q-group: rows q0 + ty*4 + qi
  const int fsw = tx & 7;         // chunk-swizzle term for this thread's K rows

  __shared__ float4 smem4[4096];             // 64KB, 16B-aligned
  char*  smem = (char*)smem4;
  float* Ksf  = (float*)smem;                // [128][128] f32, 16B-chunk swizzled
  float* Psf  = (float*)(smem + 49152);      // [128][32] f32, swizzled (aliases K rows 96..127)

  const float scale = 0.08838834764831845f;
  const float* kbase = kb + (long long)kv*T_TOK*HDIM;
  const float* vbase = vb + (long long)kv*T_TOK*HDIM;
  const float* qrow0 = qb + ((long long)h*T_TOK + q0 + ty*4)*HDIM;

  float m_[4], l_[4], O[4][4];
  #pragma unroll
  for(int qi=0;qi<4;qi++){
    m_[qi] = -1e30f; l_[qi] = 0.f;
    #pragma unroll
    for(int j=0;j<4;j++) O[qi][j] = 0.f;
  }

  for(int kt=c0; kt<c1; kt++){
    const int k0 = kt * FBK;
    __syncthreads();                          // B1: prior PV readers of Ps done
    {
      // stage K[k0 .. k0+127][0..127] -> Ksf, 16 x 1KB DMA per wave.
      const float* kcur = kbase + (long long)k0*HDIM;
      #pragma unroll
      for(int i=0;i<16;i++){
        const int rbase = (w<<5) + (i<<1);
        const int f = (i>>1) & 7;             // ((w*32+2i)>>2)&7 == (i>>1)&7
        const float* src = kcur + (long long)(rbase + (lane>>5))*HDIM
                                + (((lane&31)^f)<<2);
        gl2lds16(src, smem + rbase*512);
      }
    }
    __syncthreads();                          // B2: staged

    // ---- QK: s[qi][ki] over d, K from swizzled LDS, Q from global ----
    float s[4][4];
    #pragma unroll
    for(int qi=0;qi<4;qi++)
      #pragma unroll
      for(int ki=0;ki<4;ki++) s[qi][ki] = 0.f;

    #pragma unroll 2
    for(int dc=0; dc<32; dc++){
      float4 qv[4];
      #pragma unroll
      for(int qi=0;qi<4;qi++) qv[qi] = *(const float4*)(qrow0 + qi*HDIM + dc*4);
      float4 kf[4];
      #pragma unroll
      for(int ki=0;ki<4;ki++)
        kf[ki] = *(const float4*)&Ksf[(size_t)(4*tx+ki)*128 + ((dc ^ fsw)<<2)];
      #pragma unroll
      for(int qi=0;qi<4;qi++)
        #pragma unroll
        for(int ki=0;ki<4;ki++){
          s[qi][ki] = fmaf(qv[qi].x, kf[ki].x, s[qi][ki]);
          s[qi][ki] = fmaf(qv[qi].y, kf[ki].y, s[qi][ki]);
          s[qi][ki] = fmaf(qv[qi].z, kf[ki].z, s[qi][ki]);
          s[qi][ki] = fmaf(qv[qi].w, kf[ki].w, s[qi][ki]);
        }
    }

    // ---- scale + causal mask + online softmax (stats thread-local) ----
    const bool last = (kt == nktf-1);
    float rm[4];
    #pragma unroll
    for(int qi=0;qi<4;qi++){
      #pragma unroll
      for(int ki=0;ki<4;ki++){
        float v = s[qi][ki]*scale;
        if(last && (k0 + 4*tx + ki > q0 + ty*4 + qi)) v = -1e30f;
        s[qi][ki] = v;
      }
      rm[qi] = fmaxf(fmaxf(s[qi][0],s[qi][1]), fmaxf(s[qi][2],s[qi][3]));
    }
    #pragma unroll
    for(int o=1;o<32;o<<=1){
      #pragma unroll
      for(int qi=0;qi<4;qi++) rm[qi] = fmaxf(rm[qi], __shfl_xor(rm[qi], o));
    }
    float a_[4], rs[4];
    #pragma unroll
    for(int qi=0;qi<4;qi++){
      float mn = fmaxf(m_[qi], rm[qi]);
      a_[qi] = __expf(m_[qi] - mn);
      m_[qi] = mn;
      float r = 0.f;
      #pragma unroll
      for(int ki=0;ki<4;ki++){ s[qi][ki] = __expf(s[qi][ki] - mn); r += s[qi][ki]; }
      rs[qi] = r;
    }
    #pragma unroll
    for(int o=1;o<32;o<<=1){
      #pragma unroll
      for(int qi=0;qi<4;qi++) rs[qi] += __shfl_xor(rs[qi], o);
    }
    #pragma unroll
    for(int qi=0;qi<4;qi++){
      l_[qi] = l_[qi]*a_[qi] + rs[qi];
      #pragma unroll
      for(int j=0;j<4;j++) O[qi][j] *= a_[qi];
    }

    __syncthreads();                          // B3: all QK reads of K done -> Ps may clobber
    #pragma unroll
    for(int ki=0;ki<4;ki++){
      float4 pv;
      pv.x = s[0][ki]; pv.y = s[1][ki]; pv.z = s[2][ki]; pv.w = s[3][ki];
      *(float4*)&Psf[(size_t)(4*tx+ki)*32 + ((ty ^ fsw)<<2)] = pv;
    }
    __syncthreads();                          // B4: Ps visible

    // ---- PV: O[qi][j] += P[q][k]*V[k][d], V from global, P from LDS ----
    const float* vcur = vbase + (long long)k0*HDIM + tx*4;
    #pragma unroll 4
    for(int k=0;k<FBK;k++){
      float4 p4 = *(const float4*)&Psf[(size_t)k*32 + ((ty ^ ((k>>2)&7))<<2)];
      float4 vv = *(const float4*)(vcur + (size_t)k*HDIM);
      O[0][0]=fmaf(p4.x,vv.x,O[0][0]); O[0][1]=fmaf(p4.x,vv.y,O[0][1]);
      O[0][2]=fmaf(p4.x,vv.z,O[0][2]); O[0][3]=fmaf(p4.x,vv.w,O[0][3]);
      O[1][0]=fmaf(p4.y,vv.x,O[1][0]); O[1][1]=fmaf(p4.y,vv.y,O[1][1]);
      O[1][2]=fmaf(p4.y,vv.z,O[1][2]); O[1][3]=fmaf(p4.y,vv.w,O[1][3]);
      O[2][0]=fmaf(p4.z,vv.x,O[2][0]); O[2][1]=fmaf(p4.z,vv.y,O[2][1]);
      O[2][2]=fmaf(p4.z,vv.z,O[2][2]); O[2][3]=fmaf(p4.z,vv.w,O[2][3]);
      O[3][0]=fmaf(p4.w,vv.x,O[3][0]); O[3][1]=fmaf(p4.w,vv.y,O[3][1]);
      O[3][2]=fmaf(p4.w,vv.z,O[3][2]); O[3][3]=fmaf(p4.w,vv.w,O[3][3]);
    }
  }

  if(heavy){
    // unnormalized partial + (m,l) per row
    #pragma unroll
    for(int qi=0;qi<4;qi++){
      const int qr = q0 + ty*4 + qi - 1024;     // qt>=32 -> q >= 1024
      float* dst = Opart + ((size_t)((h<<10) + qr)*2 + pc)*128 + tx*4;
      *(float4*)dst = make_float4(O[qi][0],O[qi][1],O[qi][2],O[qi][3]);
      if(tx==0){
        float* mlp = Mpart + ((size_t)((h<<10) + qr)*2 + pc)*2;
        mlp[0] = m_[qi]; mlp[1] = l_[qi];
      }
    }
  } else {
    #pragma unroll
    for(int qi=0;qi<4;qi++){
      float inv = 1.f/l_[qi];
      float4 o4 = make_float4(O[qi][0]*inv, O[qi][1]*inv, O[qi][2]*inv, O[qi][3]*inv);
      *(float4*)(ctx + (long long)(q0 + ty*4 + qi)*(NHEAD*HDIM) + h*HDIM + tx*4) = o4;
    }
  }
}

// ---- K4b: merge two flash partials (exact fp32). 1 wave per heavy row. ----
__global__ __launch_bounds__(256) void k_fmerge(const float* __restrict__ Op,
    const float* __restrict__ Ml, float* __restrict__ ctx){
  const int wv = threadIdx.x>>6, lane = threadIdx.x&63;
  const int r = blockIdx.x*4 + wv;          // 0..8191 = h*1024 + qr
  const int h = r>>10, qr = r&1023;
  const float* o0 = Op + ((size_t)r*2+0)*128 + lane*2;
  const float* o1 = Op + ((size_t)r*2+1)*128 + lane*2;
  const float m0 = Ml[((size_t)r*2+0)*2+0], l0 = Ml[((size_t)r*2+0)*2+1];
  const float m1 = Ml[((size_t)r*2+1)*2+0], l1 = Ml[((size_t)r*2+1)*2+1];
  const float mx = fmaxf(m0,m1);
  const float a0 = __expf(m0-mx), a1 = __expf(m1-mx);
  const float li = 1.f/(l0*a0 + l1*a1);
  float2 v0 = *(const float2*)o0;
  float2 v1 = *(const float2*)o1;
  float2 o;
  o.x = (v0.x*a0 + v1.x*a1)*li;
  o.y = (v0.y*a0 + v1.y*a1)*li;
  *(float2*)(ctx + (size_t)(1024+qr)*(NHEAD*HDIM) + h*HDIM + lane*2) = o;
}

// ---- K6: read resid2 (=out1), write h2f (fp32, router) + h2b (bf16, GEMM A) ----
__global__ __launch_bounds__(256) void k_rms2(const float* __restrict__ r2,
    const float* __restrict__ w, float* __restrict__ h2f,
    unsigned short* __restrict__ h2b){
  int t = blockIdx.x, tid = threadIdx.x;
  __shared__ float sm[4];
  const long base = (long)t*H_DIM;
  float x[4]; float ss=0.f;
  #pragma unroll
  for(int i=0;i<4;i++){
    int c = tid+i*256;
    float v = r2[base+c];
    x[i]=v; ss += v*v;
  }
  float tot = bred_sum(ss, sm);
  float rms = rsqrtf(tot/(float)H_DIM + EPS_F);
  #pragma unroll
  for(int i=0;i<4;i++){
    int c = tid+i*256;
    float v = x[i]*rms*w[c];
    h2f[base+c] = v;
    h2b[base+c] = f2us(v);
  }
}

// ---- K7: router (fp32 exact) ----
__global__ __launch_bounds__(256) void k_router(const float* __restrict__ h2,
    const float* __restrict__ gw, const float* __restrict__ eb,
    int* __restrict__ topk_idx, float* __restrict__ topk_w, int* __restrict__ counts){
  int t = blockIdx.x, tid = threadIdx.x;
  int e = tid & 15, seg = tid >> 4;
  const float* hrow = h2 + (long long)t*H_DIM;
  float part = 0.f;
  #pragma unroll 4
  for(int i=0;i<64;i++){
    int hh = seg*64 + i;
    part += hrow[hh]*gw[hh*E_EXP + e];
  }
  __shared__ float pm[16][17];
  __shared__ float sS[16], sfc[16];
  pm[seg][e] = part;
  __syncthreads();
  if(tid < 16){
    float l = 0.f;
    #pragma unroll
    for(int s=0;s<16;s++) l += pm[s][tid];
    float sg = 1.f/(1.f+expf(-l));
    sS[tid]=sg; sfc[tid]=sg+eb[tid];
  }
  __syncthreads();
  if(tid==0){
    float gs[4];
    #pragma unroll
    for(int g=0; g<4; g++){
      float m1=-1e30f, m2=-1e30f;
      for(int j=0;j<4;j++){
        float v=sfc[g*4+j];
        if(v>m1){ m2=m1; m1=v; } else if(v>m2){ m2=v; }
      }
      gs[g]=m1+m2;
    }
    int g1=0; for(int g=1;g<4;g++) if(gs[g]>gs[g1]) g1=g;
    int g2=-1; for(int g=0;g<4;g++){ if(g==g1) continue; if(g2<0||gs[g]>gs[g2]) g2=g; }
    bool taken[16];
    #pragma unroll
    for(int i=0;i<16;i++) taken[i]=false;
    int idx[4];
    for(int j=0;j<4;j++){
      int best=-1; float bv=-1e30f;
      for(int i=0;i<16;i++){
        int g=i>>2;
        if(g!=g1 && g!=g2) continue;
        if(taken[i]) continue;
        if(best<0 || sfc[i]>bv){ best=i; bv=sfc[i]; }
      }
      taken[best]=true; idx[j]=best;
    }
    float w[4]; float s=0.f;
    #pragma unroll
    for(int j=0;j<4;j++){ w[j]=sS[idx[j]]; s+=w[j]; }
    s += 1e-20f;
    #pragma unroll
    for(int j=0;j<4;j++){
      topk_idx[t*4+j]=idx[j];
      topk_w[t*4+j]=w[j]/s;
      atomicAdd(&counts[idx[j]],1);
    }
  }
}

__global__ void k_zero(int* __restrict__ counts){ if(threadIdx.x<16) counts[threadIdx.x]=0; }

__global__ void k_scan(const int* __restrict__ counts, int* __restrict__ offs, int* __restrict__ cursor){
  if(threadIdx.x==0){
    int s=0;
    for(int e2=0;e2<16;e2++){ offs[e2]=s; cursor[e2]=s; s+=counts[e2]; }
    offs[16]=s;
  }
}

__global__ __launch_bounds__(256) void k_scatter(const int* __restrict__ topk_idx,
    int* __restrict__ cursor, int* __restrict__ pair_tok, int* __restrict__ tok2pair){
  int i = blockIdx.x*256 + threadIdx.x;
  int e = topk_idx[i];
  int pos = atomicAdd(&cursor[e],1);
  pair_tok[pos] = i>>2;
  tok2pair[i] = pos;
}

// ---- K15: out0 = sum_j 2*w_j*y[pair_j] + shared (bf16 in, fp32 out) ----
__global__ __launch_bounds__(256) void k_combine(const unsigned short* __restrict__ y,
    const unsigned short* __restrict__ sout, const int* __restrict__ tok2pair,
    const float* __restrict__ topk_w, float* __restrict__ out0){
  int t = blockIdx.x, tid = threadIdx.x;
  int p[4]; float w[4];
  #pragma unroll
  for(int j=0;j<4;j++){ p[j]=tok2pair[t*4+j]; w[j]=topk_w[t*4+j]*2.0f; }
  const long base = (long)t*H_DIM;
  #pragma unroll
  for(int i=0;i<4;i++){
    int c = tid + i*256;
    float v = us2f(sout[base+c]);
    #pragma unroll
    for(int j=0;j<4;j++) v += w[j]*us2f(y[(long long)p[j]*H_DIM + c]);
    out0[base+c] = v;
  }
}

extern "C" void kernel_launch(void* const* d_in, const int* in_sizes, int n_in,
                              void* d_out, int out_size, void* d_ws, size_t ws_size,
                              hipStream_t stream) {
  const float* hs   = (const float*)d_in[0];
  const float* rsd  = (const float*)d_in[1];
  const int*   pos  = (const int*)d_in[2];
  const float* ln1  = (const float*)d_in[3];
  const float* qkvw = (const float*)d_in[4];
  const float* qnw  = (const float*)d_in[5];
  const float* knw  = (const float*)d_in[6];
  const float* dw   = (const float*)d_in[7];
  const float* ln2  = (const float*)d_in[8];
  const float* gw   = (const float*)d_in[9];
  const float* eb   = (const float*)d_in[10];
  const float* w13  = (const float*)d_in[11];
  const float* w2   = (const float*)d_in[12];
  const float* wsgu = (const float*)d_in[13];
  const float* wsd  = (const float*)d_in[14];
  float* out0 = (float*)d_out;
  float* out1 = out0 + (size_t)T_TOK*H_DIM;   // resid2

  char* W = (char*)d_ws;
  float* resid = (float*)(W + 0);
  float* h     = (float*)(W + 8388608);
  float* ctx   = h;
  float* qkv   = (float*)(W + 16777216);
  float* qb    = (float*)(W + 29360128);
  float* h2f   = (float*)(W + 37748736);
  float* kb    = (float*)(W + 46137344);
  float* vb    = (float*)(W + 48234496);
  // flash split-K partials alias the dead qkv region during phase D:
  float* Opart = (float*)(W + 16777216);            // 8MB: 8*1024 rows * 2 * 128 f32
  float* Mpart = (float*)(W + 25165824);            // 128KB: 8*1024 * 2 * (m,l)
  unsigned short* gu    = (unsigned short*)(W + 8388608);
  unsigned short* ybuf  = (unsigned short*)(W + 8388608);
  unsigned short* sgu   = (unsigned short*)(W + 16777216);
  unsigned short* sact  = (unsigned short*)(W + 0);
  unsigned short* sout  = (unsigned short*)(W + 46137344);
  unsigned short* h2b   = (unsigned short*)(W + 50331648);
  unsigned short* act   = (unsigned short*)(W + 54525952);
  unsigned short* w13t  = (unsigned short*)(W + 71303168);
  unsigned short* w2t   = (unsigned short*)(W + 138412032);
  unsigned short* wsgut = (unsigned short*)(W + 171966464);
  unsigned short* wsdt  = (unsigned short*)(W + 176160768);
  float* topkw = (float*)(W + 178257920);
  int* topki   = (int*)(W + 178290688);
  int* ptok    = (int*)(W + 178323456);
  int* t2p     = (int*)(W + 178356224);
  int* cnt     = (int*)(W + 178388992);
  int* offs    = (int*)(W + 178389056);
  int* cur     = (int*)(W + 178389184);

  // 0. weight cvt + transpose -> bf16 B^T
  k_cvt_t<<<dim3(64,32,16), 256, 0, stream>>>(w13,  w13t,  1024, 2048);
  k_cvt_t<<<dim3(32,32,16), 256, 0, stream>>>(w2,   w2t,   1024, 1024);
  k_cvt_t<<<dim3(64,32,1),  256, 0, stream>>>(wsgu, wsgut, 1024, 2048);
  k_cvt_t<<<dim3(32,32,1),  256, 0, stream>>>(wsd,  wsdt,  1024, 1024);
  // A. resid + rmsnorm
  k_add_rmsnorm<<<T_TOK, 256, 0, stream>>>(hs, rsd, ln1, resid, h);
  // B. qkv = h @ qkv_w (fp32)
  gemm_f32<0><<<dim3(QKV_DIM/64, T_TOK/128), 256, 0, stream>>>(
      h, H_DIM, qkvw, QKV_DIM, qkv, QKV_DIM, nullptr, T_TOK, H_DIM);
  // C. q/k norm + rope
  k_qkv_post<<<dim3(12, T_TOK), 64, 0, stream>>>(qkv, qnw, knw, pos, qb, kb, vb);
  // D. flash attention: 768 balanced work items (split-K for heavy qtiles) + merge
  k_flash<<<dim3(NHEAD, 96), 256, 0, stream>>>(qb, kb, vb, ctx, Opart, Mpart);
  k_fmerge<<<2048, 256, 0, stream>>>(Opart, Mpart, ctx);
  // E. resid2 = ctx @ dense_w + resid -> out1 (fp32)
  gemm_f32<1><<<dim3(H_DIM/64, T_TOK/128), 256, 0, stream>>>(
      ctx, NHEAD*HDIM, dw, H_DIM, out1, H_DIM, resid, T_TOK, NHEAD*HDIM);
  // F. h2 = rmsnorm(out1)
  k_rms2<<<T_TOK, 256, 0, stream>>>(out1, ln2, h2f, h2b);
  // G. router
  k_zero<<<1, 64, 0, stream>>>(cnt);
  k_router<<<T_TOK, 256, 0, stream>>>(h2f, gw, eb, topki, topkw, cnt);
  k_scan<<<1, 64, 0, stream>>>(cnt, offs, cur);
  k_scatter<<<NPAIR/256, 256, 0, stream>>>(topki, cur, ptok, t2p);
  // H. shared expert (MFMA)
  gemm_mfma<false,false><<<dim3(16,16,1), 256, 0, stream>>>(
      h2b, 1024, wsgut, 1024, 0, sgu, 2048, nullptr, nullptr, T_TOK, 1024);
  k_silu<<<T_TOK, 256, 0, stream>>>(sgu, sact);
  gemm_mfma<false,false><<<dim3(8,16,1), 256, 0, stream>>>(
      sact, 1024, wsdt, 1024, 0, sout, 1024, nullptr, nullptr, T_TOK, 1024);
  // I. MoE expert FFN (MFMA, grouped)
  gemm_mfma<true,true><<<dim3(16,64,16), 256, 0, stream>>>(
      h2b, 1024, w13t, 1024, (long long)2048*1024, gu, 2048, ptok, offs, 0, 1024);
  k_silu<<<NPAIR, 256, 0, stream>>>(gu, act);
  gemm_mfma<true,false><<<dim3(8,64,16), 256, 0, stream>>>(
      act, 1024, w2t, 1024, (long long)1024*1024, ybuf, 1024, nullptr, offs, 0, 1024);
  // K. combine -> out0
  k_combine<<<T_TOK, 256, 0, stream>>>(ybuf, sout, t2p, topkw, out0);
}

// Round 5
// 1060.070 us; speedup vs baseline: 1.0567x; 1.0261x over previous
//
#include <hip/hip_runtime.h>
#include <hip/hip_bf16.h>

// BailingMoeBlock: T=2048 H=1024 NH=8 NKV=2 HD=128 E=16 TOPK=4 NG=4 TKG=2 F=FS=1024
// Round 9: k_flash EQUAL-CHAIN scheduling (round-8 lesson: dynamic packing of
// 4..8-unit items still gave ~14-unit makespan vs 8.5 ideal; occupancy 15%).
//  - Flatten work into units (head,qtile,ktile): 4352 units total.
//  - Exactly 512 blocks (2/CU, all co-resident), block b owns units
//    [floor(8.5b), floor(8.5(b+1))) = 8..9 units -> makespan 9 by construction.
//  - A q-tile row spans <=3 blocks; part slot j = b - (2S+1)/17 closed-form.
//    Slot0 -> unnormalized ctx in place; slots1/2 -> dead qkv/h2f scratch.
//  - k_fmerge: 1 wave per q-row, exact fp32 combine+normalize for ALL rows.
//  - Per-unit core (DMA swizzle staging, 4qx4k/4qx4d, Ps exchange) identical
//    to round 8. Everything outside flash identical to round 8.

#define T_TOK 2048
#define H_DIM 1024
#define NHEAD 8
#define NKVH 2
#define HDIM 128
#define QKV_DIM 1536
#define E_EXP 16
#define TOPKE 4
#define F_DIM 1024
#define FS_DIM 1024
#define NPAIR (T_TOK*TOPKE)
#define EPS_F 1e-6f

#define DEV __device__ __forceinline__

typedef __attribute__((ext_vector_type(4))) float f32x4;
typedef __attribute__((ext_vector_type(8))) short s16x8;

DEV float us2f(unsigned short u){ return __uint_as_float(((unsigned int)u)<<16); }
DEV unsigned short f2us(float f){
  __hip_bfloat16 b = __float2bfloat16(f);
  unsigned short u; __builtin_memcpy(&u,&b,2); return u;
}

DEV void gl2lds16(const void* g, void* l){
  __builtin_amdgcn_global_load_lds(
      (const __attribute__((address_space(1))) void*)g,
      (__attribute__((address_space(3))) void*)l, 16, 0, 0);
}

// cumulative units before q-tile qt (per head): C(qt) = (a+1)*(2a+b), a=qt>>2,b=qt&3
DEV int crow(int qt){ int a=qt>>2, b=qt&3; return (a+1)*(2*a+b); }

// ---- block reductions (256 threads = 4 waves) ----
DEV float bred_sum(float v, float* sm){
  #pragma unroll
  for(int o=32;o>0;o>>=1) v += __shfl_down(v,o);
  int w = threadIdx.x>>6, l = threadIdx.x&63;
  __syncthreads();
  if(l==0) sm[w]=v;
  __syncthreads();
  return sm[0]+sm[1]+sm[2]+sm[3];
}

// ---- weight cvt+transpose: out[z][n][k] = bf16(in[z][k][n]) ----
__global__ __launch_bounds__(256) void k_cvt_t(const float* __restrict__ in,
    unsigned short* __restrict__ out, int Kd, int Nd){
  const int z = blockIdx.z;
  const int kb = blockIdx.y*32, nb = blockIdx.x*32;
  __shared__ float Lt[32][33];
  const int tid = threadIdx.x;
  const int r = tid>>3, c4 = (tid&7)*4;
  const float* src = in + (long long)z*Kd*Nd + (long long)(kb+r)*Nd + nb + c4;
  float4 v = *(const float4*)src;
  Lt[r][c4+0]=v.x; Lt[r][c4+1]=v.y; Lt[r][c4+2]=v.z; Lt[r][c4+3]=v.w;
  __syncthreads();
  ushort4 o;
  o.x = f2us(Lt[c4+0][r]); o.y = f2us(Lt[c4+1][r]);
  o.z = f2us(Lt[c4+2][r]); o.w = f2us(Lt[c4+3][r]);
  *(ushort4*)(out + (long long)z*Nd*Kd + (long long)(nb+r)*Kd + kb + c4) = o;
}

// ---- MFMA GEMM: C[M x N](bf16) = A[M x K](bf16, opt gather) * Bt[N x K]^T ----
template<bool GROUPED, bool GATHER>
__global__ __launch_bounds__(256) void gemm_mfma(
    const unsigned short* __restrict__ A, int lda,
    const unsigned short* __restrict__ Bt, int ldbt, long long bstride,
    unsigned short* __restrict__ C, int ldc,
    const int* __restrict__ rowidx, const int* __restrict__ grpoff,
    int Mdense, int K){
  const int z = blockIdx.z;
  const int rb = GROUPED ? grpoff[z] : 0;
  const int re = GROUPED ? grpoff[z+1] : Mdense;
  const int m0 = rb + blockIdx.y*128;
  if(m0 >= re) return;
  const int n0 = blockIdx.x*128;
  const unsigned short* Bz = Bt + (long long)z*bstride;

  __shared__ unsigned short As[128][32];   // [m][k] 8KB
  __shared__ unsigned short Bs[128][32];   // [n][k] 8KB

  const int tid = threadIdx.x;
  const int s0 = tid, s1 = tid+256;
  int gr0 = m0 + (s0>>2), gr1 = m0 + (s1>>2);
  if(GROUPED){ gr0 = min(gr0, re-1); gr1 = min(gr1, re-1); }
  if(GATHER){ gr0 = rowidx[gr0]; gr1 = rowidx[gr1]; }
  const unsigned short* ag0 = A + (long long)gr0*lda + (s0&3)*8;
  const unsigned short* ag1 = A + (long long)gr1*lda + (s1&3)*8;
  const unsigned short* bg0 = Bz + (long long)(n0 + (s0>>2))*ldbt + (s0&3)*8;
  const unsigned short* bg1 = Bz + (long long)(n0 + (s1>>2))*ldbt + (s1&3)*8;
  char* asb = (char*)&As[0][0];
  char* bsb = (char*)&Bs[0][0];
  const int wb = (tid & 192)*16;

  const int w = tid>>6, lane = tid&63;
  const int wm = (w>>1)*64, wn = (w&1)*64;
  const int fr = lane&15, q8 = (lane>>4)*8;

  f32x4 zero = {0.f,0.f,0.f,0.f};
  f32x4 acc[4][4];
  #pragma unroll
  for(int mi=0;mi<4;mi++)
    #pragma unroll
    for(int ni=0;ni<4;ni++) acc[mi][ni]=zero;

  for(int k0=0;k0<K;k0+=32){
    __syncthreads();
    gl2lds16(ag0 + k0, asb + wb);
    gl2lds16(ag1 + k0, asb + 4096 + wb);
    gl2lds16(bg0 + k0, bsb + wb);
    gl2lds16(bg1 + k0, bsb + 4096 + wb);
    __syncthreads();
    s16x8 af[4], bf[4];
    #pragma unroll
    for(int mi=0;mi<4;mi++) af[mi] = *(const s16x8*)&As[wm+mi*16+fr][q8];
    #pragma unroll
    for(int ni=0;ni<4;ni++) bf[ni] = *(const s16x8*)&Bs[wn+ni*16+fr][q8];
    #pragma unroll
    for(int mi=0;mi<4;mi++)
      #pragma unroll
      for(int ni=0;ni<4;ni++)
        acc[mi][ni] = __builtin_amdgcn_mfma_f32_16x16x32_bf16(af[mi], bf[ni], acc[mi][ni], 0,0,0);
  }
  const int q4 = (lane>>4)*4;
  #pragma unroll
  for(int mi=0;mi<4;mi++)
    #pragma unroll
    for(int ni=0;ni<4;ni++){
      const int col = n0 + wn + ni*16 + fr;
      #pragma unroll
      for(int r=0;r<4;r++){
        const int row = m0 + wm + mi*16 + q4 + r;
        if(row < re) C[(long long)row*ldc + col] = f2us(acc[mi][ni][r]);
      }
    }
}

// ---- silu-mul ----
__global__ __launch_bounds__(256) void k_silu(const unsigned short* __restrict__ gu,
    unsigned short* __restrict__ act){
  const int r = blockIdx.x, c = threadIdx.x*4;
  const ushort4 g4 = *(const ushort4*)(gu + (long long)r*2048 + c);
  const ushort4 u4 = *(const ushort4*)(gu + (long long)r*2048 + 1024 + c);
  float g[4] = {us2f(g4.x),us2f(g4.y),us2f(g4.z),us2f(g4.w)};
  float u[4] = {us2f(u4.x),us2f(u4.y),us2f(u4.z),us2f(u4.w)};
  ushort4 o;
  o.x = f2us((g[0]/(1.f+__expf(-g[0])))*u[0]);
  o.y = f2us((g[1]/(1.f+__expf(-g[1])))*u[1]);
  o.z = f2us((g[2]/(1.f+__expf(-g[2])))*u[2]);
  o.w = f2us((g[3]/(1.f+__expf(-g[3])))*u[3]);
  *(ushort4*)(act + (long long)r*1024 + c) = o;
}

// ---- K1: resid = hs + residual ; h = rmsnorm(resid, ln1_w) ----
__global__ __launch_bounds__(256) void k_add_rmsnorm(const float* __restrict__ hs,
    const float* __restrict__ rs, const float* __restrict__ w,
    float* __restrict__ resid, float* __restrict__ h){
  int t = blockIdx.x, tid = threadIdx.x;
  __shared__ float sm[4];
  const long base = (long)t*H_DIM;
  float x[4]; float ss = 0.f;
  #pragma unroll
  for(int i=0;i<4;i++){
    int c = tid + i*256;
    float v = hs[base+c] + rs[base+c];
    x[i]=v; resid[base+c]=v; ss += v*v;
  }
  float tot = bred_sum(ss, sm);
  float rms = rsqrtf(tot/(float)H_DIM + EPS_F);
  #pragma unroll
  for(int i=0;i<4;i++){
    int c = tid + i*256;
    h[base+c] = x[i]*rms*w[c];
  }
}

// ---- fp32 GEMM (QKV + dense only): C = A*B (+D) ----
template<int EPI_ADD>
__global__ __launch_bounds__(256) void gemm_f32(
    const float* __restrict__ A, int lda,
    const float* __restrict__ B, int ldb,
    float* __restrict__ C, int ldc,
    const float* __restrict__ D, int M, int K){
  const int m0 = blockIdx.y*128;
  const int n0 = blockIdx.x*64;
  __shared__ float As[16][132];
  __shared__ float Bs[16][65];
  float acc[8][4];
  #pragma unroll
  for(int i=0;i<8;i++)
    #pragma unroll
    for(int j=0;j<4;j++) acc[i][j]=0.f;
  const int tid = threadIdx.x;
  const int tx = tid & 15, ty = tid >> 4;
  const int ar = tid >> 1, ac = (tid & 1)*8;
  const int brr = tid >> 4, bc = (tid & 15)*4;
  const float* Aptr = A + (long long)(m0+ar)*lda;
  for(int k0=0;k0<K;k0+=16){
    float4 a0 = *(const float4*)(Aptr + k0 + ac);
    float4 a1 = *(const float4*)(Aptr + k0 + ac + 4);
    float4 bv = *(const float4*)(B + (long long)(k0+brr)*ldb + n0 + bc);
    __syncthreads();
    As[ac+0][ar]=a0.x; As[ac+1][ar]=a0.y; As[ac+2][ar]=a0.z; As[ac+3][ar]=a0.w;
    As[ac+4][ar]=a1.x; As[ac+5][ar]=a1.y; As[ac+6][ar]=a1.z; As[ac+7][ar]=a1.w;
    Bs[brr][bc+0]=bv.x; Bs[brr][bc+1]=bv.y; Bs[brr][bc+2]=bv.z; Bs[brr][bc+3]=bv.w;
    __syncthreads();
    #pragma unroll
    for(int kk=0;kk<16;kk++){
      float a[8], b[4];
      #pragma unroll
      for(int i=0;i<8;i++) a[i]=As[kk][ty*8+i];
      #pragma unroll
      for(int j=0;j<4;j++) b[j]=Bs[kk][tx*4+j];
      #pragma unroll
      for(int i=0;i<8;i++)
        #pragma unroll
        for(int j=0;j<4;j++) acc[i][j] = fmaf(a[i], b[j], acc[i][j]);
    }
  }
  #pragma unroll
  for(int i=0;i<8;i++){
    int r = m0 + ty*8 + i;
    float* crow = C + (long long)r*ldc + n0 + tx*4;
    float4 v = make_float4(acc[i][0],acc[i][1],acc[i][2],acc[i][3]);
    if(EPI_ADD){
      const float4 d = *(const float4*)(D + (long long)r*ldc + n0 + tx*4);
      v.x+=d.x; v.y+=d.y; v.z+=d.z; v.w+=d.w;
    }
    *(float4*)crow = v;
  }
}

// ---- K3: per-(t,slot) q/k rmsnorm + rope, v copy. 64 threads. ----
__global__ __launch_bounds__(64) void k_qkv_post(const float* __restrict__ qkv,
    const float* __restrict__ qw, const float* __restrict__ kw,
    const int* __restrict__ pos,
    float* __restrict__ qb, float* __restrict__ kb, float* __restrict__ vb){
  int slot = blockIdx.x, t = blockIdx.y, lane = threadIdx.x;
  const float* x = qkv + (long long)t*QKV_DIM + slot*HDIM;
  float x0 = x[lane], x1 = x[lane+64];
  if(slot < 10){
    float ss = x0*x0 + x1*x1;
    #pragma unroll
    for(int o=32;o>0;o>>=1) ss += __shfl_xor(ss,o);
    float rms = rsqrtf(ss/(float)HDIM + EPS_F);
    const float* w = (slot<8)? qw : kw;
    float n0 = x0*rms*w[lane];
    float n1 = x1*rms*w[lane+64];
    float p = (float)pos[t];
    float invf = __expf(-((float)lane/64.f)*9.210340371976184f);
    float ang = p*invf;
    float s = sinf(ang), c = cosf(ang);
    float o0 = n0*c - n1*s;
    float o1 = n1*c + n0*s;
    float* dst = (slot<8)? (qb + ((long long)slot*T_TOK + t)*HDIM)
                         : (kb + ((long long)(slot-8)*T_TOK + t)*HDIM);
    dst[lane]=o0; dst[lane+64]=o1;
  } else {
    float* dst = vb + ((long long)(slot-10)*T_TOK + t)*HDIM;
    dst[lane]=x0; dst[lane+64]=x1;
  }
}

// ---- K4: flash attention (fp32), round-9 equal-chain structure ----
// 512 blocks, all co-resident (2/CU). Block b owns global units
// [ (17b)>>1, (17(b+1))>>1 ) over the flattened (h, qt, kt) space
// (544 units/head, ascending qt, ascending kt). Segments flushed as
// unnormalized partials; slot j = b - bS(row) in {0,1,2}.
#define FBQ 32
#define FBK 128
__global__ __launch_bounds__(256,2) void k_flash(const float* __restrict__ qb,
    const float* __restrict__ kb, const float* __restrict__ vb,
    float* __restrict__ ctx, float* __restrict__ Op1, float* __restrict__ Op2,
    float* __restrict__ Ml){
  const int b = blockIdx.x;
  const int u0 = (17*b)>>1, u1 = (17*(b+1))>>1;
  const int tid = threadIdx.x;
  const int lane = tid & 63;
  const int w = tid >> 6;
  const int tx = tid & 31;        // k-group (QK) / d-group (PV)
  const int ty = tid >> 5;        // q-group: rows q0 + ty*4 + qi
  const int fsw = tx & 7;         // chunk-swizzle term for this thread's K rows

  __shared__ float4 smem4[4096];             // 64KB, 16B-aligned
  char*  smem = (char*)smem4;
  float* Ksf  = (float*)smem;                // [128][128] f32, 16B-chunk swizzled
  float* Psf  = (float*)(smem + 49152);      // [128][32] f32, swizzled (aliases K rows 96..127)

  const float scale = 0.08838834764831845f;

  // locate starting (h, qt, kt)
  int h = u0/544;
  int r = u0 - h*544;
  int qt = 0;
  while(qt < 63 && crow(qt+1) <= r) qt++;
  int kt = r - crow(qt);

  int u = u0;
  while(u < u1){
    const int nkt = (qt>>2) + 1;
    const int q0 = qt * FBQ;
    const int kv = h >> 2;
    const float* kbase = kb + (long long)kv*T_TOK*HDIM;
    const float* vbase = vb + (long long)kv*T_TOK*HDIM;
    const float* qrow0 = qb + ((long long)h*T_TOK + q0 + ty*4)*HDIM;
    const int segN = min(nkt - kt, u1 - u);
    const int ktEnd = kt + segN;

    float m_[4], l_[4], O[4][4];
    #pragma unroll
    for(int qi=0;qi<4;qi++){
      m_[qi] = -1e30f; l_[qi] = 0.f;
      #pragma unroll
      for(int j=0;j<4;j++) O[qi][j] = 0.f;
    }

    for(; kt<ktEnd; kt++){
      const int k0 = kt * FBK;
      __syncthreads();                          // B1: prior PV readers of Ps done
      {
        // stage K[k0 .. k0+127][0..127] -> Ksf, 16 x 1KB DMA per wave.
        const float* kcur = kbase + (long long)k0*HDIM;
        #pragma unroll
        for(int i=0;i<16;i++){
          const int rbase = (w<<5) + (i<<1);
          const int f = (i>>1) & 7;             // ((w*32+2i)>>2)&7 == (i>>1)&7
          const float* src = kcur + (long long)(rbase + (lane>>5))*HDIM
                                  + (((lane&31)^f)<<2);
          gl2lds16(src, smem + rbase*512);
        }
      }
      __syncthreads();                          // B2: staged

      // ---- QK: s[qi][ki] over d, K from swizzled LDS, Q from global ----
      float s[4][4];
      #pragma unroll
      for(int qi=0;qi<4;qi++)
        #pragma unroll
        for(int ki=0;ki<4;ki++) s[qi][ki] = 0.f;

      #pragma unroll 2
      for(int dc=0; dc<32; dc++){
        float4 qv[4];
        #pragma unroll
        for(int qi=0;qi<4;qi++) qv[qi] = *(const float4*)(qrow0 + qi*HDIM + dc*4);
        float4 kf[4];
        #pragma unroll
        for(int ki=0;ki<4;ki++)
          kf[ki] = *(const float4*)&Ksf[(size_t)(4*tx+ki)*128 + ((dc ^ fsw)<<2)];
        #pragma unroll
        for(int qi=0;qi<4;qi++)
          #pragma unroll
          for(int ki=0;ki<4;ki++){
            s[qi][ki] = fmaf(qv[qi].x, kf[ki].x, s[qi][ki]);
            s[qi][ki] = fmaf(qv[qi].y, kf[ki].y, s[qi][ki]);
            s[qi][ki] = fmaf(qv[qi].z, kf[ki].z, s[qi][ki]);
            s[qi][ki] = fmaf(qv[qi].w, kf[ki].w, s[qi][ki]);
          }
      }

      // ---- scale + causal mask + online softmax (stats thread-local) ----
      const bool last = (kt == nkt-1);
      float rm[4];
      #pragma unroll
      for(int qi=0;qi<4;qi++){
        #pragma unroll
        for(int ki=0;ki<4;ki++){
          float v = s[qi][ki]*scale;
          if(last && (k0 + 4*tx + ki > q0 + ty*4 + qi)) v = -1e30f;
          s[qi][ki] = v;
        }
        rm[qi] = fmaxf(fmaxf(s[qi][0],s[qi][1]), fmaxf(s[qi][2],s[qi][3]));
      }
      #pragma unroll
      for(int o=1;o<32;o<<=1){
        #pragma unroll
        for(int qi=0;qi<4;qi++) rm[qi] = fmaxf(rm[qi], __shfl_xor(rm[qi], o));
      }
      float a_[4], rs[4];
      #pragma unroll
      for(int qi=0;qi<4;qi++){
        float mn = fmaxf(m_[qi], rm[qi]);
        a_[qi] = __expf(m_[qi] - mn);
        m_[qi] = mn;
        float rr = 0.f;
        #pragma unroll
        for(int ki=0;ki<4;ki++){ s[qi][ki] = __expf(s[qi][ki] - mn); rr += s[qi][ki]; }
        rs[qi] = rr;
      }
      #pragma unroll
      for(int o=1;o<32;o<<=1){
        #pragma unroll
        for(int qi=0;qi<4;qi++) rs[qi] += __shfl_xor(rs[qi], o);
      }
      #pragma unroll
      for(int qi=0;qi<4;qi++){
        l_[qi] = l_[qi]*a_[qi] + rs[qi];
        #pragma unroll
        for(int j=0;j<4;j++) O[qi][j] *= a_[qi];
      }

      __syncthreads();                          // B3: QK reads of K done -> Ps may clobber
      #pragma unroll
      for(int ki=0;ki<4;ki++){
        float4 pv;
        pv.x = s[0][ki]; pv.y = s[1][ki]; pv.z = s[2][ki]; pv.w = s[3][ki];
        *(float4*)&Psf[(size_t)(4*tx+ki)*32 + ((ty ^ fsw)<<2)] = pv;
      }
      __syncthreads();                          // B4: Ps visible

      // ---- PV: O[qi][j] += P[q][k]*V[k][d], V from global, P from LDS ----
      const float* vcur = vbase + (long long)k0*HDIM + tx*4;
      #pragma unroll 4
      for(int k=0;k<FBK;k++){
        float4 p4 = *(const float4*)&Psf[(size_t)k*32 + ((ty ^ ((k>>2)&7))<<2)];
        float4 vv = *(const float4*)(vcur + (size_t)k*HDIM);
        O[0][0]=fmaf(p4.x,vv.x,O[0][0]); O[0][1]=fmaf(p4.x,vv.y,O[0][1]);
        O[0][2]=fmaf(p4.x,vv.z,O[0][2]); O[0][3]=fmaf(p4.x,vv.w,O[0][3]);
        O[1][0]=fmaf(p4.y,vv.x,O[1][0]); O[1][1]=fmaf(p4.y,vv.y,O[1][1]);
        O[1][2]=fmaf(p4.y,vv.z,O[1][2]); O[1][3]=fmaf(p4.y,vv.w,O[1][3]);
        O[2][0]=fmaf(p4.z,vv.x,O[2][0]); O[2][1]=fmaf(p4.z,vv.y,O[2][1]);
        O[2][2]=fmaf(p4.z,vv.z,O[2][2]); O[2][3]=fmaf(p4.z,vv.w,O[2][3]);
        O[3][0]=fmaf(p4.w,vv.x,O[3][0]); O[3][1]=fmaf(p4.w,vv.y,O[3][1]);
        O[3][2]=fmaf(p4.w,vv.z,O[3][2]); O[3][3]=fmaf(p4.w,vv.w,O[3][3]);
      }
    }

    // ---- flush segment: unnormalized partial to slot j ----
    {
      const int R = (h<<6) + qt;
      const int S = h*544 + crow(qt);
      const int bS = (2*S+1)/17;
      const int j = b - bS;                      // 0..2
      #pragma unroll
      for(int qi=0;qi<4;qi++){
        const int row = ty*4 + qi;
        float4 o4 = make_float4(O[qi][0],O[qi][1],O[qi][2],O[qi][3]);
        if(j==0){
          *(float4*)(ctx + (long long)(q0+row)*(NHEAD*HDIM) + h*HDIM + tx*4) = o4;
        } else if(j==1){
          *(float4*)(Op1 + (long long)R*4096 + row*128 + tx*4) = o4;
        } else {
          *(float4*)(Op2 + (long long)R*4096 + row*128 + tx*4) = o4;
        }
        if(tx==0){
          Ml[((R*3+j)<<6) + row*2 + 0] = m_[qi];
          Ml[((R*3+j)<<6) + row*2 + 1] = l_[qi];
        }
      }
    }

    u += segN;
    if(ktEnd == nkt){ kt = 0; qt++; if(qt == 64){ qt = 0; h++; } }
    else kt = ktEnd;
  }
}

// ---- K4b: merge/normalize flash partials (exact fp32). 1 wave per q-row. ----
__global__ __launch_bounds__(256) void k_fmerge(float* __restrict__ ctx,
    const float* __restrict__ Op1, const float* __restrict__ Op2,
    const float* __restrict__ Ml){
  const int wv = threadIdx.x>>6, lane = threadIdx.x&63;
  const int gr = blockIdx.x*4 + wv;          // 0..16383
  const int R = gr>>5, q = gr&31;
  const int h = R>>6, qt = R&63;
  const int nkt = (qt>>2)+1;
  const int S = h*544 + crow(qt);
  const int bS = (2*S+1)/17;
  const int bE = (2*(S+nkt-1)+1)/17;
  const int parts = bE - bS + 1;
  float* dst = ctx + (long long)(qt*32+q)*(NHEAD*HDIM) + h*HDIM + lane*2;
  float2 o0 = *(float2*)dst;
  const float* mlb = Ml + ((R*3)<<6) + q*2;
  const float m0 = mlb[0], l0 = mlb[1];
  float ox, oy;
  if(parts == 1){
    float inv = 1.f/l0;
    ox = o0.x*inv; oy = o0.y*inv;
  } else {
    const float m1 = mlb[64], l1 = mlb[65];
    float2 o1 = *(const float2*)(Op1 + (long long)R*4096 + q*128 + lane*2);
    if(parts == 2){
      float mx = fmaxf(m0,m1);
      float a0 = __expf(m0-mx), a1 = __expf(m1-mx);
      float inv = 1.f/(l0*a0 + l1*a1);
      ox = (o0.x*a0 + o1.x*a1)*inv;
      oy = (o0.y*a0 + o1.y*a1)*inv;
    } else {
      const float m2 = mlb[128], l2 = mlb[129];
      float2 o2 = *(const float2*)(Op2 + (long long)R*4096 + q*128 + lane*2);
      float mx = fmaxf(fmaxf(m0,m1),m2);
      float a0 = __expf(m0-mx), a1 = __expf(m1-mx), a2 = __expf(m2-mx);
      float inv = 1.f/(l0*a0 + l1*a1 + l2*a2);
      ox = (o0.x*a0 + o1.x*a1 + o2.x*a2)*inv;
      oy = (o0.y*a0 + o1.y*a1 + o2.y*a2)*inv;
    }
  }
  dst[0] = ox; dst[1] = oy;
}

// ---- K6: read resid2 (=out1), write h2f (fp32, router) + h2b (bf16, GEMM A) ----
__global__ __launch_bounds__(256) void k_rms2(const float* __restrict__ r2,
    const float* __restrict__ w, float* __restrict__ h2f,
    unsigned short* __restrict__ h2b){
  int t = blockIdx.x, tid = threadIdx.x;
  __shared__ float sm[4];
  const long base = (long)t*H_DIM;
  float x[4]; float ss=0.f;
  #pragma unroll
  for(int i=0;i<4;i++){
    int c = tid+i*256;
    float v = r2[base+c];
    x[i]=v; ss += v*v;
  }
  float tot = bred_sum(ss, sm);
  float rms = rsqrtf(tot/(float)H_DIM + EPS_F);
  #pragma unroll
  for(int i=0;i<4;i++){
    int c = tid+i*256;
    float v = x[i]*rms*w[c];
    h2f[base+c] = v;
    h2b[base+c] = f2us(v);
  }
}

// ---- K7: router (fp32 exact) ----
__global__ __launch_bounds__(256) void k_router(const float* __restrict__ h2,
    const float* __restrict__ gw, const float* __restrict__ eb,
    int* __restrict__ topk_idx, float* __restrict__ topk_w, int* __restrict__ counts){
  int t = blockIdx.x, tid = threadIdx.x;
  int e = tid & 15, seg = tid >> 4;
  const float* hrow = h2 + (long long)t*H_DIM;
  float part = 0.f;
  #pragma unroll 4
  for(int i=0;i<64;i++){
    int hh = seg*64 + i;
    part += hrow[hh]*gw[hh*E_EXP + e];
  }
  __shared__ float pm[16][17];
  __shared__ float sS[16], sfc[16];
  pm[seg][e] = part;
  __syncthreads();
  if(tid < 16){
    float l = 0.f;
    #pragma unroll
    for(int s=0;s<16;s++) l += pm[s][tid];
    float sg = 1.f/(1.f+expf(-l));
    sS[tid]=sg; sfc[tid]=sg+eb[tid];
  }
  __syncthreads();
  if(tid==0){
    float gs[4];
    #pragma unroll
    for(int g=0; g<4; g++){
      float m1=-1e30f, m2=-1e30f;
      for(int j=0;j<4;j++){
        float v=sfc[g*4+j];
        if(v>m1){ m2=m1; m1=v; } else if(v>m2){ m2=v; }
      }
      gs[g]=m1+m2;
    }
    int g1=0; for(int g=1;g<4;g++) if(gs[g]>gs[g1]) g1=g;
    int g2=-1; for(int g=0;g<4;g++){ if(g==g1) continue; if(g2<0||gs[g]>gs[g2]) g2=g; }
    bool taken[16];
    #pragma unroll
    for(int i=0;i<16;i++) taken[i]=false;
    int idx[4];
    for(int j=0;j<4;j++){
      int best=-1; float bv=-1e30f;
      for(int i=0;i<16;i++){
        int g=i>>2;
        if(g!=g1 && g!=g2) continue;
        if(taken[i]) continue;
        if(best<0 || sfc[i]>bv){ best=i; bv=sfc[i]; }
      }
      taken[best]=true; idx[j]=best;
    }
    float w[4]; float s=0.f;
    #pragma unroll
    for(int j=0;j<4;j++){ w[j]=sS[idx[j]]; s+=w[j]; }
    s += 1e-20f;
    #pragma unroll
    for(int j=0;j<4;j++){
      topk_idx[t*4+j]=idx[j];
      topk_w[t*4+j]=w[j]/s;
      atomicAdd(&counts[idx[j]],1);
    }
  }
}

__global__ void k_zero(int* __restrict__ counts){ if(threadIdx.x<16) counts[threadIdx.x]=0; }

__global__ void k_scan(const int* __restrict__ counts, int* __restrict__ offs, int* __restrict__ cursor){
  if(threadIdx.x==0){
    int s=0;
    for(int e2=0;e2<16;e2++){ offs[e2]=s; cursor[e2]=s; s+=counts[e2]; }
    offs[16]=s;
  }
}

__global__ __launch_bounds__(256) void k_scatter(const int* __restrict__ topk_idx,
    int* __restrict__ cursor, int* __restrict__ pair_tok, int* __restrict__ tok2pair){
  int i = blockIdx.x*256 + threadIdx.x;
  int e = topk_idx[i];
  int pos = atomicAdd(&cursor[e],1);
  pair_tok[pos] = i>>2;
  tok2pair[i] = pos;
}

// ---- K15: out0 = sum_j 2*w_j*y[pair_j] + shared (bf16 in, fp32 out) ----
__global__ __launch_bounds__(256) void k_combine(const unsigned short* __restrict__ y,
    const unsigned short* __restrict__ sout, const int* __restrict__ tok2pair,
    const float* __restrict__ topk_w, float* __restrict__ out0){
  int t = blockIdx.x, tid = threadIdx.x;
  int p[4]; float w[4];
  #pragma unroll
  for(int j=0;j<4;j++){ p[j]=tok2pair[t*4+j]; w[j]=topk_w[t*4+j]*2.0f; }
  const long base = (long)t*H_DIM;
  #pragma unroll
  for(int i=0;i<4;i++){
    int c = tid + i*256;
    float v = us2f(sout[base+c]);
    #pragma unroll
    for(int j=0;j<4;j++) v += w[j]*us2f(y[(long long)p[j]*H_DIM + c]);
    out0[base+c] = v;
  }
}

extern "C" void kernel_launch(void* const* d_in, const int* in_sizes, int n_in,
                              void* d_out, int out_size, void* d_ws, size_t ws_size,
                              hipStream_t stream) {
  const float* hs   = (const float*)d_in[0];
  const float* rsd  = (const float*)d_in[1];
  const int*   pos  = (const int*)d_in[2];
  const float* ln1  = (const float*)d_in[3];
  const float* qkvw = (const float*)d_in[4];
  const float* qnw  = (const float*)d_in[5];
  const float* knw  = (const float*)d_in[6];
  const float* dw   = (const float*)d_in[7];
  const float* ln2  = (const float*)d_in[8];
  const float* gw   = (const float*)d_in[9];
  const float* eb   = (const float*)d_in[10];
  const float* w13  = (const float*)d_in[11];
  const float* w2   = (const float*)d_in[12];
  const float* wsgu = (const float*)d_in[13];
  const float* wsd  = (const float*)d_in[14];
  float* out0 = (float*)d_out;
  float* out1 = out0 + (size_t)T_TOK*H_DIM;   // resid2

  char* W = (char*)d_ws;
  float* resid = (float*)(W + 0);
  float* h     = (float*)(W + 8388608);
  float* ctx   = h;
  float* qkv   = (float*)(W + 16777216);
  float* qb    = (float*)(W + 29360128);
  float* h2f   = (float*)(W + 37748736);
  float* kb    = (float*)(W + 46137344);
  float* vb    = (float*)(W + 48234496);
  // flash partial scratch (phase D only; qkv and h2f regions are dead then):
  float* Op1   = (float*)(W + 16777216);            // 8MB: 512 qt-rows * 32q * 128d f32
  float* Ml    = (float*)(W + 25165824);            // 384KB: 512 * 3 slots * 64 f32
  float* Op2   = (float*)(W + 37748736);            // 8MB (h2f region, dead in D)
  unsigned short* gu    = (unsigned short*)(W + 8388608);
  unsigned short* ybuf  = (unsigned short*)(W + 8388608);
  unsigned short* sgu   = (unsigned short*)(W + 16777216);
  unsigned short* sact  = (unsigned short*)(W + 0);
  unsigned short* sout  = (unsigned short*)(W + 46137344);
  unsigned short* h2b   = (unsigned short*)(W + 50331648);
  unsigned short* act   = (unsigned short*)(W + 54525952);
  unsigned short* w13t  = (unsigned short*)(W + 71303168);
  unsigned short* w2t   = (unsigned short*)(W + 138412032);
  unsigned short* wsgut = (unsigned short*)(W + 171966464);
  unsigned short* wsdt  = (unsigned short*)(W + 176160768);
  float* topkw = (float*)(W + 178257920);
  int* topki   = (int*)(W + 178290688);
  int* ptok    = (int*)(W + 178323456);
  int* t2p     = (int*)(W + 178356224);
  int* cnt     = (int*)(W + 178388992);
  int* offs    = (int*)(W + 178389056);
  int* cur     = (int*)(W + 178389184);

  // 0. weight cvt + transpose -> bf16 B^T
  k_cvt_t<<<dim3(64,32,16), 256, 0, stream>>>(w13,  w13t,  1024, 2048);
  k_cvt_t<<<dim3(32,32,16), 256, 0, stream>>>(w2,   w2t,   1024, 1024);
  k_cvt_t<<<dim3(64,32,1),  256, 0, stream>>>(wsgu, wsgut, 1024, 2048);
  k_cvt_t<<<dim3(32,32,1),  256, 0, stream>>>(wsd,  wsdt,  1024, 1024);
  // A. resid + rmsnorm
  k_add_rmsnorm<<<T_TOK, 256, 0, stream>>>(hs, rsd, ln1, resid, h);
  // B. qkv = h @ qkv_w (fp32)
  gemm_f32<0><<<dim3(QKV_DIM/64, T_TOK/128), 256, 0, stream>>>(
      h, H_DIM, qkvw, QKV_DIM, qkv, QKV_DIM, nullptr, T_TOK, H_DIM);
  // C. q/k norm + rope
  k_qkv_post<<<dim3(12, T_TOK), 64, 0, stream>>>(qkv, qnw, knw, pos, qb, kb, vb);
  // D. flash attention: 512 equal chains (8-9 units) + uniform merge
  k_flash<<<512, 256, 0, stream>>>(qb, kb, vb, ctx, Op1, Op2, Ml);
  k_fmerge<<<4096, 256, 0, stream>>>(ctx, Op1, Op2, Ml);
  // E. resid2 = ctx @ dense_w + resid -> out1 (fp32)
  gemm_f32<1><<<dim3(H_DIM/64, T_TOK/128), 256, 0, stream>>>(
      ctx, NHEAD*HDIM, dw, H_DIM, out1, H_DIM, resid, T_TOK, NHEAD*HDIM);
  // F. h2 = rmsnorm(out1)
  k_rms2<<<T_TOK, 256, 0, stream>>>(out1, ln2, h2f, h2b);
  // G. router
  k_zero<<<1, 64, 0, stream>>>(cnt);
  k_router<<<T_TOK, 256, 0, stream>>>(h2f, gw, eb, topki, topkw, cnt);
  k_scan<<<1, 64, 0, stream>>>(cnt, offs, cur);
  k_scatter<<<NPAIR/256, 256, 0, stream>>>(topki, cur, ptok, t2p);
  // H. shared expert (MFMA)
  gemm_mfma<false,false><<<dim3(16,16,1), 256, 0, stream>>>(
      h2b, 1024, wsgut, 1024, 0, sgu, 2048, nullptr, nullptr, T_TOK, 1024);
  k_silu<<<T_TOK, 256, 0, stream>>>(sgu, sact);
  gemm_mfma<false,false><<<dim3(8,16,1), 256, 0, stream>>>(
      sact, 1024, wsdt, 1024, 0, sout, 1024, nullptr, nullptr, T_TOK, 1024);
  // I. MoE expert FFN (MFMA, grouped)
  gemm_mfma<true,true><<<dim3(16,64,16), 256, 0, stream>>>(
      h2b, 1024, w13t, 1024, (long long)2048*1024, gu, 2048, ptok, offs, 0, 1024);
  k_silu<<<NPAIR, 256, 0, stream>>>(gu, act);
  gemm_mfma<true,false><<<dim3(8,64,16), 256, 0, stream>>>(
      act, 1024, w2t, 1024, (long long)1024*1024, ybuf, 1024, nullptr, offs, 0, 1024);
  // K. combine -> out0
  k_combine<<<T_TOK, 256, 0, stream>>>(ybuf, sout, t2p, topkw, out0);
}

// Round 6
// 935.832 us; speedup vs baseline: 1.1970x; 1.1328x over previous
//
#include <hip/hip_runtime.h>
#include <hip/hip_bf16.h>

// BailingMoeBlock: T=2048 H=1024 NH=8 NKV=2 HD=128 E=16 TOPK=4 NG=4 TKG=2 F=FS=1024
// Round 10: QKV + dense GEMMs converted from fp32 SIMT to bf16x3 split MFMA
// (x = hi + lo, C = hh + hl + lh; dropped lo*lo term ~2^-18 -> ~1e-5 relative,
// attenuated ~4x before router: flip risk negligible). gemm_mfma3 is a clone
// of the proven gemm_mfma skeleton with 4 staged tiles (A/B x hi/lo, 32KB LDS),
// 48 MFMA/K-step, fp32 epilogue (+resid for dense).
//  - k_add_rmsnorm emits a_hi/a_lo (bf16) instead of h fp32.
//  - k_fmerge emits ctx_hi/ctx_lo (bf16) for the dense GEMM A operand.
//  - k_cvt_t3 splits qkv_w / dense_w into B^T hi/lo (phase-checked aliasing:
//    qkvwt in h2f/Op2 region [used at B, scribbled at D], dwt in h2b region
//    [used at E, written at F]).
// k_flash / MoE / shared expert identical to round 9.

#define T_TOK 2048
#define H_DIM 1024
#define NHEAD 8
#define NKVH 2
#define HDIM 128
#define QKV_DIM 1536
#define E_EXP 16
#define TOPKE 4
#define F_DIM 1024
#define FS_DIM 1024
#define NPAIR (T_TOK*TOPKE)
#define EPS_F 1e-6f

#define DEV __device__ __forceinline__

typedef __attribute__((ext_vector_type(4))) float f32x4;
typedef __attribute__((ext_vector_type(8))) short s16x8;

DEV float us2f(unsigned short u){ return __uint_as_float(((unsigned int)u)<<16); }
DEV unsigned short f2us(float f){
  __hip_bfloat16 b = __float2bfloat16(f);
  unsigned short u; __builtin_memcpy(&u,&b,2); return u;
}

DEV void gl2lds16(const void* g, void* l){
  __builtin_amdgcn_global_load_lds(
      (const __attribute__((address_space(1))) void*)g,
      (__attribute__((address_space(3))) void*)l, 16, 0, 0);
}

// cumulative units before q-tile qt (per head): C(qt) = (a+1)*(2a+b), a=qt>>2,b=qt&3
DEV int crow(int qt){ int a=qt>>2, b=qt&3; return (a+1)*(2*a+b); }

// ---- block reductions (256 threads = 4 waves) ----
DEV float bred_sum(float v, float* sm){
  #pragma unroll
  for(int o=32;o>0;o>>=1) v += __shfl_down(v,o);
  int w = threadIdx.x>>6, l = threadIdx.x&63;
  __syncthreads();
  if(l==0) sm[w]=v;
  __syncthreads();
  return sm[0]+sm[1]+sm[2]+sm[3];
}

// ---- weight cvt+transpose: out[z][n][k] = bf16(in[z][k][n]) ----
__global__ __launch_bounds__(256) void k_cvt_t(const float* __restrict__ in,
    unsigned short* __restrict__ out, int Kd, int Nd){
  const int z = blockIdx.z;
  const int kb = blockIdx.y*32, nb = blockIdx.x*32;
  __shared__ float Lt[32][33];
  const int tid = threadIdx.x;
  const int r = tid>>3, c4 = (tid&7)*4;
  const float* src = in + (long long)z*Kd*Nd + (long long)(kb+r)*Nd + nb + c4;
  float4 v = *(const float4*)src;
  Lt[r][c4+0]=v.x; Lt[r][c4+1]=v.y; Lt[r][c4+2]=v.z; Lt[r][c4+3]=v.w;
  __syncthreads();
  ushort4 o;
  o.x = f2us(Lt[c4+0][r]); o.y = f2us(Lt[c4+1][r]);
  o.z = f2us(Lt[c4+2][r]); o.w = f2us(Lt[c4+3][r]);
  *(ushort4*)(out + (long long)z*Nd*Kd + (long long)(nb+r)*Kd + kb + c4) = o;
}

// ---- weight cvt+transpose+SPLIT: oh/ol[n][k] = hi/lo bf16 of in[k][n] ----
__global__ __launch_bounds__(256) void k_cvt_t3(const float* __restrict__ in,
    unsigned short* __restrict__ oh, unsigned short* __restrict__ ol,
    int Kd, int Nd){
  const int kb = blockIdx.y*32, nb = blockIdx.x*32;
  __shared__ float Lt[32][33];
  const int tid = threadIdx.x;
  const int r = tid>>3, c4 = (tid&7)*4;
  const float* src = in + (long long)(kb+r)*Nd + nb + c4;
  float4 v = *(const float4*)src;
  Lt[r][c4+0]=v.x; Lt[r][c4+1]=v.y; Lt[r][c4+2]=v.z; Lt[r][c4+3]=v.w;
  __syncthreads();
  ushort4 h4, l4;
  float f;
  f = Lt[c4+0][r]; h4.x = f2us(f); l4.x = f2us(f - us2f(h4.x));
  f = Lt[c4+1][r]; h4.y = f2us(f); l4.y = f2us(f - us2f(h4.y));
  f = Lt[c4+2][r]; h4.z = f2us(f); l4.z = f2us(f - us2f(h4.z));
  f = Lt[c4+3][r]; h4.w = f2us(f); l4.w = f2us(f - us2f(h4.w));
  const long long ob = (long long)(nb+r)*Kd + kb + c4;
  *(ushort4*)(oh + ob) = h4;
  *(ushort4*)(ol + ob) = l4;
}

// ---- MFMA GEMM: C[M x N](bf16) = A[M x K](bf16, opt gather) * Bt[N x K]^T ----
template<bool GROUPED, bool GATHER>
__global__ __launch_bounds__(256) void gemm_mfma(
    const unsigned short* __restrict__ A, int lda,
    const unsigned short* __restrict__ Bt, int ldbt, long long bstride,
    unsigned short* __restrict__ C, int ldc,
    const int* __restrict__ rowidx, const int* __restrict__ grpoff,
    int Mdense, int K){
  const int z = blockIdx.z;
  const int rb = GROUPED ? grpoff[z] : 0;
  const int re = GROUPED ? grpoff[z+1] : Mdense;
  const int m0 = rb + blockIdx.y*128;
  if(m0 >= re) return;
  const int n0 = blockIdx.x*128;
  const unsigned short* Bz = Bt + (long long)z*bstride;

  __shared__ unsigned short As[128][32];   // [m][k] 8KB
  __shared__ unsigned short Bs[128][32];   // [n][k] 8KB

  const int tid = threadIdx.x;
  const int s0 = tid, s1 = tid+256;
  int gr0 = m0 + (s0>>2), gr1 = m0 + (s1>>2);
  if(GROUPED){ gr0 = min(gr0, re-1); gr1 = min(gr1, re-1); }
  if(GATHER){ gr0 = rowidx[gr0]; gr1 = rowidx[gr1]; }
  const unsigned short* ag0 = A + (long long)gr0*lda + (s0&3)*8;
  const unsigned short* ag1 = A + (long long)gr1*lda + (s1&3)*8;
  const unsigned short* bg0 = Bz + (long long)(n0 + (s0>>2))*ldbt + (s0&3)*8;
  const unsigned short* bg1 = Bz + (long long)(n0 + (s1>>2))*ldbt + (s1&3)*8;
  char* asb = (char*)&As[0][0];
  char* bsb = (char*)&Bs[0][0];
  const int wb = (tid & 192)*16;

  const int w = tid>>6, lane = tid&63;
  const int wm = (w>>1)*64, wn = (w&1)*64;
  const int fr = lane&15, q8 = (lane>>4)*8;

  f32x4 zero = {0.f,0.f,0.f,0.f};
  f32x4 acc[4][4];
  #pragma unroll
  for(int mi=0;mi<4;mi++)
    #pragma unroll
    for(int ni=0;ni<4;ni++) acc[mi][ni]=zero;

  for(int k0=0;k0<K;k0+=32){
    __syncthreads();
    gl2lds16(ag0 + k0, asb + wb);
    gl2lds16(ag1 + k0, asb + 4096 + wb);
    gl2lds16(bg0 + k0, bsb + wb);
    gl2lds16(bg1 + k0, bsb + 4096 + wb);
    __syncthreads();
    s16x8 af[4], bf[4];
    #pragma unroll
    for(int mi=0;mi<4;mi++) af[mi] = *(const s16x8*)&As[wm+mi*16+fr][q8];
    #pragma unroll
    for(int ni=0;ni<4;ni++) bf[ni] = *(const s16x8*)&Bs[wn+ni*16+fr][q8];
    #pragma unroll
    for(int mi=0;mi<4;mi++)
      #pragma unroll
      for(int ni=0;ni<4;ni++)
        acc[mi][ni] = __builtin_amdgcn_mfma_f32_16x16x32_bf16(af[mi], bf[ni], acc[mi][ni], 0,0,0);
  }
  const int q4 = (lane>>4)*4;
  #pragma unroll
  for(int mi=0;mi<4;mi++)
    #pragma unroll
    for(int ni=0;ni<4;ni++){
      const int col = n0 + wn + ni*16 + fr;
      #pragma unroll
      for(int r=0;r<4;r++){
        const int row = m0 + wm + mi*16 + q4 + r;
        if(row < re) C[(long long)row*ldc + col] = f2us(acc[mi][ni][r]);
      }
    }
}

// ---- bf16x3 split MFMA GEMM: C[M x N](f32) = A(hi+lo) * B^T(hi+lo), drop lo*lo ----
template<int EPI_ADD>
__global__ __launch_bounds__(256) void gemm_mfma3(
    const unsigned short* __restrict__ Ah, const unsigned short* __restrict__ Al, int lda,
    const unsigned short* __restrict__ Bh, const unsigned short* __restrict__ Bl, int ldbt,
    float* __restrict__ C, int ldc, const float* __restrict__ D, int K){
  const int m0 = blockIdx.y*128;
  const int n0 = blockIdx.x*128;

  __shared__ unsigned short Ash[128][32];
  __shared__ unsigned short Asl[128][32];
  __shared__ unsigned short Bsh[128][32];
  __shared__ unsigned short Bsl[128][32];

  const int tid = threadIdx.x;
  const int s0 = tid, s1 = tid+256;
  const long long ar0 = (long long)(m0 + (s0>>2))*lda + (s0&3)*8;
  const long long ar1 = (long long)(m0 + (s1>>2))*lda + (s1&3)*8;
  const long long br0 = (long long)(n0 + (s0>>2))*ldbt + (s0&3)*8;
  const long long br1 = (long long)(n0 + (s1>>2))*ldbt + (s1&3)*8;
  char* ahb = (char*)&Ash[0][0];
  char* alb = (char*)&Asl[0][0];
  char* bhb = (char*)&Bsh[0][0];
  char* blb = (char*)&Bsl[0][0];
  const int wb = (tid & 192)*16;

  const int w = tid>>6, lane = tid&63;
  const int wm = (w>>1)*64, wn = (w&1)*64;
  const int fr = lane&15, q8 = (lane>>4)*8;

  f32x4 zero = {0.f,0.f,0.f,0.f};
  f32x4 acc[4][4];
  #pragma unroll
  for(int mi=0;mi<4;mi++)
    #pragma unroll
    for(int ni=0;ni<4;ni++) acc[mi][ni]=zero;

  for(int k0=0;k0<K;k0+=32){
    __syncthreads();
    gl2lds16(Ah + ar0 + k0, ahb + wb);
    gl2lds16(Ah + ar1 + k0, ahb + 4096 + wb);
    gl2lds16(Al + ar0 + k0, alb + wb);
    gl2lds16(Al + ar1 + k0, alb + 4096 + wb);
    gl2lds16(Bh + br0 + k0, bhb + wb);
    gl2lds16(Bh + br1 + k0, bhb + 4096 + wb);
    gl2lds16(Bl + br0 + k0, blb + wb);
    gl2lds16(Bl + br1 + k0, blb + 4096 + wb);
    __syncthreads();
    s16x8 afh[4], afl[4], bfh[4], bfl[4];
    #pragma unroll
    for(int mi=0;mi<4;mi++){
      afh[mi] = *(const s16x8*)&Ash[wm+mi*16+fr][q8];
      afl[mi] = *(const s16x8*)&Asl[wm+mi*16+fr][q8];
    }
    #pragma unroll
    for(int ni=0;ni<4;ni++){
      bfh[ni] = *(const s16x8*)&Bsh[wn+ni*16+fr][q8];
      bfl[ni] = *(const s16x8*)&Bsl[wn+ni*16+fr][q8];
    }
    #pragma unroll
    for(int mi=0;mi<4;mi++)
      #pragma unroll
      for(int ni=0;ni<4;ni++){
        acc[mi][ni] = __builtin_amdgcn_mfma_f32_16x16x32_bf16(afh[mi], bfh[ni], acc[mi][ni], 0,0,0);
        acc[mi][ni] = __builtin_amdgcn_mfma_f32_16x16x32_bf16(afh[mi], bfl[ni], acc[mi][ni], 0,0,0);
        acc[mi][ni] = __builtin_amdgcn_mfma_f32_16x16x32_bf16(afl[mi], bfh[ni], acc[mi][ni], 0,0,0);
      }
  }
  const int q4 = (lane>>4)*4;
  #pragma unroll
  for(int mi=0;mi<4;mi++)
    #pragma unroll
    for(int ni=0;ni<4;ni++){
      const int col = n0 + wn + ni*16 + fr;
      #pragma unroll
      for(int r=0;r<4;r++){
        const int row = m0 + wm + mi*16 + q4 + r;
        float v = acc[mi][ni][r];
        if(EPI_ADD) v += D[(long long)row*ldc + col];
        C[(long long)row*ldc + col] = v;
      }
    }
}

// ---- silu-mul ----
__global__ __launch_bounds__(256) void k_silu(const unsigned short* __restrict__ gu,
    unsigned short* __restrict__ act){
  const int r = blockIdx.x, c = threadIdx.x*4;
  const ushort4 g4 = *(const ushort4*)(gu + (long long)r*2048 + c);
  const ushort4 u4 = *(const ushort4*)(gu + (long long)r*2048 + 1024 + c);
  float g[4] = {us2f(g4.x),us2f(g4.y),us2f(g4.z),us2f(g4.w)};
  float u[4] = {us2f(u4.x),us2f(u4.y),us2f(u4.z),us2f(u4.w)};
  ushort4 o;
  o.x = f2us((g[0]/(1.f+__expf(-g[0])))*u[0]);
  o.y = f2us((g[1]/(1.f+__expf(-g[1])))*u[1]);
  o.z = f2us((g[2]/(1.f+__expf(-g[2])))*u[2]);
  o.w = f2us((g[3]/(1.f+__expf(-g[3])))*u[3]);
  *(ushort4*)(act + (long long)r*1024 + c) = o;
}

// ---- K1: resid = hs + residual ; a_hi/a_lo = bf16x2 split of rmsnorm(resid) ----
__global__ __launch_bounds__(256) void k_add_rmsnorm(const float* __restrict__ hs,
    const float* __restrict__ rs, const float* __restrict__ w,
    float* __restrict__ resid, unsigned short* __restrict__ ah,
    unsigned short* __restrict__ al){
  int t = blockIdx.x, tid = threadIdx.x;
  __shared__ float sm[4];
  const long base = (long)t*H_DIM;
  float x[4]; float ss = 0.f;
  #pragma unroll
  for(int i=0;i<4;i++){
    int c = tid + i*256;
    float v = hs[base+c] + rs[base+c];
    x[i]=v; resid[base+c]=v; ss += v*v;
  }
  float tot = bred_sum(ss, sm);
  float rms = rsqrtf(tot/(float)H_DIM + EPS_F);
  #pragma unroll
  for(int i=0;i<4;i++){
    int c = tid + i*256;
    float v = x[i]*rms*w[c];
    unsigned short hh = f2us(v);
    ah[base+c] = hh;
    al[base+c] = f2us(v - us2f(hh));
  }
}

// ---- K3: per-(t,slot) q/k rmsnorm + rope, v copy. 64 threads. ----
__global__ __launch_bounds__(64) void k_qkv_post(const float* __restrict__ qkv,
    const float* __restrict__ qw, const float* __restrict__ kw,
    const int* __restrict__ pos,
    float* __restrict__ qb, float* __restrict__ kb, float* __restrict__ vb){
  int slot = blockIdx.x, t = blockIdx.y, lane = threadIdx.x;
  const float* x = qkv + (long long)t*QKV_DIM + slot*HDIM;
  float x0 = x[lane], x1 = x[lane+64];
  if(slot < 10){
    float ss = x0*x0 + x1*x1;
    #pragma unroll
    for(int o=32;o>0;o>>=1) ss += __shfl_xor(ss,o);
    float rms = rsqrtf(ss/(float)HDIM + EPS_F);
    const float* w = (slot<8)? qw : kw;
    float n0 = x0*rms*w[lane];
    float n1 = x1*rms*w[lane+64];
    float p = (float)pos[t];
    float invf = __expf(-((float)lane/64.f)*9.210340371976184f);
    float ang = p*invf;
    float s = sinf(ang), c = cosf(ang);
    float o0 = n0*c - n1*s;
    float o1 = n1*c + n0*s;
    float* dst = (slot<8)? (qb + ((long long)slot*T_TOK + t)*HDIM)
                         : (kb + ((long long)(slot-8)*T_TOK + t)*HDIM);
    dst[lane]=o0; dst[lane+64]=o1;
  } else {
    float* dst = vb + ((long long)(slot-10)*T_TOK + t)*HDIM;
    dst[lane]=x0; dst[lane+64]=x1;
  }
}

// ---- K4: flash attention (fp32), round-9 equal-chain structure (unchanged) ----
#define FBQ 32
#define FBK 128
__global__ __launch_bounds__(256,2) void k_flash(const float* __restrict__ qb,
    const float* __restrict__ kb, const float* __restrict__ vb,
    float* __restrict__ ctx, float* __restrict__ Op1, float* __restrict__ Op2,
    float* __restrict__ Ml){
  const int b = blockIdx.x;
  const int u0 = (17*b)>>1, u1 = (17*(b+1))>>1;
  const int tid = threadIdx.x;
  const int lane = tid & 63;
  const int w = tid >> 6;
  const int tx = tid & 31;        // k-group (QK) / d-group (PV)
  const int ty = tid >> 5;        // q-group: rows q0 + ty*4 + qi
  const int fsw = tx & 7;         // chunk-swizzle term for this thread's K rows

  __shared__ float4 smem4[4096];             // 64KB, 16B-aligned
  char*  smem = (char*)smem4;
  float* Ksf  = (float*)smem;                // [128][128] f32, 16B-chunk swizzled
  float* Psf  = (float*)(smem + 49152);      // [128][32] f32, swizzled (aliases K rows 96..127)

  const float scale = 0.08838834764831845f;

  // locate starting (h, qt, kt)
  int h = u0/544;
  int r = u0 - h*544;
  int qt = 0;
  while(qt < 63 && crow(qt+1) <= r) qt++;
  int kt = r - crow(qt);

  int u = u0;
  while(u < u1){
    const int nkt = (qt>>2) + 1;
    const int q0 = qt * FBQ;
    const int kv = h >> 2;
    const float* kbase = kb + (long long)kv*T_TOK*HDIM;
    const float* vbase = vb + (long long)kv*T_TOK*HDIM;
    const float* qrow0 = qb + ((long long)h*T_TOK + q0 + ty*4)*HDIM;
    const int segN = min(nkt - kt, u1 - u);
    const int ktEnd = kt + segN;

    float m_[4], l_[4], O[4][4];
    #pragma unroll
    for(int qi=0;qi<4;qi++){
      m_[qi] = -1e30f; l_[qi] = 0.f;
      #pragma unroll
      for(int j=0;j<4;j++) O[qi][j] = 0.f;
    }

    for(; kt<ktEnd; kt++){
      const int k0 = kt * FBK;
      __syncthreads();                          // B1: prior PV readers of Ps done
      {
        const float* kcur = kbase + (long long)k0*HDIM;
        #pragma unroll
        for(int i=0;i<16;i++){
          const int rbase = (w<<5) + (i<<1);
          const int f = (i>>1) & 7;             // ((w*32+2i)>>2)&7 == (i>>1)&7
          const float* src = kcur + (long long)(rbase + (lane>>5))*HDIM
                                  + (((lane&31)^f)<<2);
          gl2lds16(src, smem + rbase*512);
        }
      }
      __syncthreads();                          // B2: staged

      // ---- QK: s[qi][ki] over d, K from swizzled LDS, Q from global ----
      float s[4][4];
      #pragma unroll
      for(int qi=0;qi<4;qi++)
        #pragma unroll
        for(int ki=0;ki<4;ki++) s[qi][ki] = 0.f;

      #pragma unroll 2
      for(int dc=0; dc<32; dc++){
        float4 qv[4];
        #pragma unroll
        for(int qi=0;qi<4;qi++) qv[qi] = *(const float4*)(qrow0 + qi*HDIM + dc*4);
        float4 kf[4];
        #pragma unroll
        for(int ki=0;ki<4;ki++)
          kf[ki] = *(const float4*)&Ksf[(size_t)(4*tx+ki)*128 + ((dc ^ fsw)<<2)];
        #pragma unroll
        for(int qi=0;qi<4;qi++)
          #pragma unroll
          for(int ki=0;ki<4;ki++){
            s[qi][ki] = fmaf(qv[qi].x, kf[ki].x, s[qi][ki]);
            s[qi][ki] = fmaf(qv[qi].y, kf[ki].y, s[qi][ki]);
            s[qi][ki] = fmaf(qv[qi].z, kf[ki].z, s[qi][ki]);
            s[qi][ki] = fmaf(qv[qi].w, kf[ki].w, s[qi][ki]);
          }
      }

      // ---- scale + causal mask + online softmax (stats thread-local) ----
      const bool last = (kt == nkt-1);
      float rm[4];
      #pragma unroll
      for(int qi=0;qi<4;qi++){
        #pragma unroll
        for(int ki=0;ki<4;ki++){
          float v = s[qi][ki]*scale;
          if(last && (k0 + 4*tx + ki > q0 + ty*4 + qi)) v = -1e30f;
          s[qi][ki] = v;
        }
        rm[qi] = fmaxf(fmaxf(s[qi][0],s[qi][1]), fmaxf(s[qi][2],s[qi][3]));
      }
      #pragma unroll
      for(int o=1;o<32;o<<=1){
        #pragma unroll
        for(int qi=0;qi<4;qi++) rm[qi] = fmaxf(rm[qi], __shfl_xor(rm[qi], o));
      }
      float a_[4], rs[4];
      #pragma unroll
      for(int qi=0;qi<4;qi++){
        float mn = fmaxf(m_[qi], rm[qi]);
        a_[qi] = __expf(m_[qi] - mn);
        m_[qi] = mn;
        float rr = 0.f;
        #pragma unroll
        for(int ki=0;ki<4;ki++){ s[qi][ki] = __expf(s[qi][ki] - mn); rr += s[qi][ki]; }
        rs[qi] = rr;
      }
      #pragma unroll
      for(int o=1;o<32;o<<=1){
        #pragma unroll
        for(int qi=0;qi<4;qi++) rs[qi] += __shfl_xor(rs[qi], o);
      }
      #pragma unroll
      for(int qi=0;qi<4;qi++){
        l_[qi] = l_[qi]*a_[qi] + rs[qi];
        #pragma unroll
        for(int j=0;j<4;j++) O[qi][j] *= a_[qi];
      }

      __syncthreads();                          // B3: QK reads of K done -> Ps may clobber
      #pragma unroll
      for(int ki=0;ki<4;ki++){
        float4 pv;
        pv.x = s[0][ki]; pv.y = s[1][ki]; pv.z = s[2][ki]; pv.w = s[3][ki];
        *(float4*)&Psf[(size_t)(4*tx+ki)*32 + ((ty ^ fsw)<<2)] = pv;
      }
      __syncthreads();                          // B4: Ps visible

      // ---- PV: O[qi][j] += P[q][k]*V[k][d], V from global, P from LDS ----
      const float* vcur = vbase + (long long)k0*HDIM + tx*4;
      #pragma unroll 4
      for(int k=0;k<FBK;k++){
        float4 p4 = *(const float4*)&Psf[(size_t)k*32 + ((ty ^ ((k>>2)&7))<<2)];
        float4 vv = *(const float4*)(vcur + (size_t)k*HDIM);
        O[0][0]=fmaf(p4.x,vv.x,O[0][0]); O[0][1]=fmaf(p4.x,vv.y,O[0][1]);
        O[0][2]=fmaf(p4.x,vv.z,O[0][2]); O[0][3]=fmaf(p4.x,vv.w,O[0][3]);
        O[1][0]=fmaf(p4.y,vv.x,O[1][0]); O[1][1]=fmaf(p4.y,vv.y,O[1][1]);
        O[1][2]=fmaf(p4.y,vv.z,O[1][2]); O[1][3]=fmaf(p4.y,vv.w,O[1][3]);
        O[2][0]=fmaf(p4.z,vv.x,O[2][0]); O[2][1]=fmaf(p4.z,vv.y,O[2][1]);
        O[2][2]=fmaf(p4.z,vv.z,O[2][2]); O[2][3]=fmaf(p4.z,vv.w,O[2][3]);
        O[3][0]=fmaf(p4.w,vv.x,O[3][0]); O[3][1]=fmaf(p4.w,vv.y,O[3][1]);
        O[3][2]=fmaf(p4.w,vv.z,O[3][2]); O[3][3]=fmaf(p4.w,vv.w,O[3][3]);
      }
    }

    // ---- flush segment: unnormalized partial to slot j ----
    {
      const int R = (h<<6) + qt;
      const int S = h*544 + crow(qt);
      const int bS = (2*S+1)/17;
      const int j = b - bS;                      // 0..2
      #pragma unroll
      for(int qi=0;qi<4;qi++){
        const int row = ty*4 + qi;
        float4 o4 = make_float4(O[qi][0],O[qi][1],O[qi][2],O[qi][3]);
        if(j==0){
          *(float4*)(ctx + (long long)(q0+row)*(NHEAD*HDIM) + h*HDIM + tx*4) = o4;
        } else if(j==1){
          *(float4*)(Op1 + (long long)R*4096 + row*128 + tx*4) = o4;
        } else {
          *(float4*)(Op2 + (long long)R*4096 + row*128 + tx*4) = o4;
        }
        if(tx==0){
          Ml[((R*3+j)<<6) + row*2 + 0] = m_[qi];
          Ml[((R*3+j)<<6) + row*2 + 1] = l_[qi];
        }
      }
    }

    u += segN;
    if(ktEnd == nkt){ kt = 0; qt++; if(qt == 64){ qt = 0; h++; } }
    else kt = ktEnd;
  }
}

// ---- K4b: merge/normalize flash partials -> ctx_hi/ctx_lo bf16 split ----
__global__ __launch_bounds__(256) void k_fmerge(const float* __restrict__ ctx,
    const float* __restrict__ Op1, const float* __restrict__ Op2,
    const float* __restrict__ Ml, unsigned short* __restrict__ ch,
    unsigned short* __restrict__ cl){
  const int wv = threadIdx.x>>6, lane = threadIdx.x&63;
  const int gr = blockIdx.x*4 + wv;          // 0..16383
  const int R = gr>>5, q = gr&31;
  const int h = R>>6, qt = R&63;
  const int nkt = (qt>>2)+1;
  const int S = h*544 + crow(qt);
  const int bS = (2*S+1)/17;
  const int bE = (2*(S+nkt-1)+1)/17;
  const int parts = bE - bS + 1;
  const float* src0 = ctx + (long long)(qt*32+q)*(NHEAD*HDIM) + h*HDIM + lane*2;
  float2 o0 = *(const float2*)src0;
  const float* mlb = Ml + ((R*3)<<6) + q*2;
  const float m0 = mlb[0], l0 = mlb[1];
  float ox, oy;
  if(parts == 1){
    float inv = 1.f/l0;
    ox = o0.x*inv; oy = o0.y*inv;
  } else {
    const float m1 = mlb[64], l1 = mlb[65];
    float2 o1 = *(const float2*)(Op1 + (long long)R*4096 + q*128 + lane*2);
    if(parts == 2){
      float mx = fmaxf(m0,m1);
      float a0 = __expf(m0-mx), a1 = __expf(m1-mx);
      float inv = 1.f/(l0*a0 + l1*a1);
      ox = (o0.x*a0 + o1.x*a1)*inv;
      oy = (o0.y*a0 + o1.y*a1)*inv;
    } else {
      const float m2 = mlb[128], l2 = mlb[129];
      float2 o2 = *(const float2*)(Op2 + (long long)R*4096 + q*128 + lane*2);
      float mx = fmaxf(fmaxf(m0,m1),m2);
      float a0 = __expf(m0-mx), a1 = __expf(m1-mx), a2 = __expf(m2-mx);
      float inv = 1.f/(l0*a0 + l1*a1 + l2*a2);
      ox = (o0.x*a0 + o1.x*a1 + o2.x*a2)*inv;
      oy = (o0.y*a0 + o1.y*a1 + o2.y*a2)*inv;
    }
  }
  const long long idx = (long long)(qt*32+q)*(NHEAD*HDIM) + h*HDIM + lane*2;
  unsigned short hx = f2us(ox), hy = f2us(oy);
  ch[idx] = hx;   cl[idx] = f2us(ox - us2f(hx));
  ch[idx+1] = hy; cl[idx+1] = f2us(oy - us2f(hy));
}

// ---- K6: read resid2 (=out1), write h2f (fp32, router) + h2b (bf16, GEMM A) ----
__global__ __launch_bounds__(256) void k_rms2(const float* __restrict__ r2,
    const float* __restrict__ w, float* __restrict__ h2f,
    unsigned short* __restrict__ h2b){
  int t = blockIdx.x, tid = threadIdx.x;
  __shared__ float sm[4];
  const long base = (long)t*H_DIM;
  float x[4]; float ss=0.f;
  #pragma unroll
  for(int i=0;i<4;i++){
    int c = tid+i*256;
    float v = r2[base+c];
    x[i]=v; ss += v*v;
  }
  float tot = bred_sum(ss, sm);
  float rms = rsqrtf(tot/(float)H_DIM + EPS_F);
  #pragma unroll
  for(int i=0;i<4;i++){
    int c = tid+i*256;
    float v = x[i]*rms*w[c];
    h2f[base+c] = v;
    h2b[base+c] = f2us(v);
  }
}

// ---- K7: router (fp32 exact) ----
__global__ __launch_bounds__(256) void k_router(const float* __restrict__ h2,
    const float* __restrict__ gw, const float* __restrict__ eb,
    int* __restrict__ topk_idx, float* __restrict__ topk_w, int* __restrict__ counts){
  int t = blockIdx.x, tid = threadIdx.x;
  int e = tid & 15, seg = tid >> 4;
  const float* hrow = h2 + (long long)t*H_DIM;
  float part = 0.f;
  #pragma unroll 4
  for(int i=0;i<64;i++){
    int hh = seg*64 + i;
    part += hrow[hh]*gw[hh*E_EXP + e];
  }
  __shared__ float pm[16][17];
  __shared__ float sS[16], sfc[16];
  pm[seg][e] = part;
  __syncthreads();
  if(tid < 16){
    float l = 0.f;
    #pragma unroll
    for(int s=0;s<16;s++) l += pm[s][tid];
    float sg = 1.f/(1.f+expf(-l));
    sS[tid]=sg; sfc[tid]=sg+eb[tid];
  }
  __syncthreads();
  if(tid==0){
    float gs[4];
    #pragma unroll
    for(int g=0; g<4; g++){
      float m1=-1e30f, m2=-1e30f;
      for(int j=0;j<4;j++){
        float v=sfc[g*4+j];
        if(v>m1){ m2=m1; m1=v; } else if(v>m2){ m2=v; }
      }
      gs[g]=m1+m2;
    }
    int g1=0; for(int g=1;g<4;g++) if(gs[g]>gs[g1]) g1=g;
    int g2=-1; for(int g=0;g<4;g++){ if(g==g1) continue; if(g2<0||gs[g]>gs[g2]) g2=g; }
    bool taken[16];
    #pragma unroll
    for(int i=0;i<16;i++) taken[i]=false;
    int idx[4];
    for(int j=0;j<4;j++){
      int best=-1; float bv=-1e30f;
      for(int i=0;i<16;i++){
        int g=i>>2;
        if(g!=g1 && g!=g2) continue;
        if(taken[i]) continue;
        if(best<0 || sfc[i]>bv){ best=i; bv=sfc[i]; }
      }
      taken[best]=true; idx[j]=best;
    }
    float w[4]; float s=0.f;
    #pragma unroll
    for(int j=0;j<4;j++){ w[j]=sS[idx[j]]; s+=w[j]; }
    s += 1e-20f;
    #pragma unroll
    for(int j=0;j<4;j++){
      topk_idx[t*4+j]=idx[j];
      topk_w[t*4+j]=w[j]/s;
      atomicAdd(&counts[idx[j]],1);
    }
  }
}

__global__ void k_zero(int* __restrict__ counts){ if(threadIdx.x<16) counts[threadIdx.x]=0; }

__global__ void k_scan(const int* __restrict__ counts, int* __restrict__ offs, int* __restrict__ cursor){
  if(threadIdx.x==0){
    int s=0;
    for(int e2=0;e2<16;e2++){ offs[e2]=s; cursor[e2]=s; s+=counts[e2]; }
    offs[16]=s;
  }
}

__global__ __launch_bounds__(256) void k_scatter(const int* __restrict__ topk_idx,
    int* __restrict__ cursor, int* __restrict__ pair_tok, int* __restrict__ tok2pair){
  int i = blockIdx.x*256 + threadIdx.x;
  int e = topk_idx[i];
  int pos = atomicAdd(&cursor[e],1);
  pair_tok[pos] = i>>2;
  tok2pair[i] = pos;
}

// ---- K15: out0 = sum_j 2*w_j*y[pair_j] + shared (bf16 in, fp32 out) ----
__global__ __launch_bounds__(256) void k_combine(const unsigned short* __restrict__ y,
    const unsigned short* __restrict__ sout, const int* __restrict__ tok2pair,
    const float* __restrict__ topk_w, float* __restrict__ out0){
  int t = blockIdx.x, tid = threadIdx.x;
  int p[4]; float w[4];
  #pragma unroll
  for(int j=0;j<4;j++){ p[j]=tok2pair[t*4+j]; w[j]=topk_w[t*4+j]*2.0f; }
  const long base = (long)t*H_DIM;
  #pragma unroll
  for(int i=0;i<4;i++){
    int c = tid + i*256;
    float v = us2f(sout[base+c]);
    #pragma unroll
    for(int j=0;j<4;j++) v += w[j]*us2f(y[(long long)p[j]*H_DIM + c]);
    out0[base+c] = v;
  }
}

extern "C" void kernel_launch(void* const* d_in, const int* in_sizes, int n_in,
                              void* d_out, int out_size, void* d_ws, size_t ws_size,
                              hipStream_t stream) {
  const float* hs   = (const float*)d_in[0];
  const float* rsd  = (const float*)d_in[1];
  const int*   pos  = (const int*)d_in[2];
  const float* ln1  = (const float*)d_in[3];
  const float* qkvw = (const float*)d_in[4];
  const float* qnw  = (const float*)d_in[5];
  const float* knw  = (const float*)d_in[6];
  const float* dw   = (const float*)d_in[7];
  const float* ln2  = (const float*)d_in[8];
  const float* gw   = (const float*)d_in[9];
  const float* eb   = (const float*)d_in[10];
  const float* w13  = (const float*)d_in[11];
  const float* w2   = (const float*)d_in[12];
  const float* wsgu = (const float*)d_in[13];
  const float* wsd  = (const float*)d_in[14];
  float* out0 = (float*)d_out;
  float* out1 = out0 + (size_t)T_TOK*H_DIM;   // resid2

  char* W = (char*)d_ws;
  float* resid = (float*)(W + 0);
  // h region (8MB @ 8388608): a_hi/a_lo during A..B; flash unnorm ctx during D.
  unsigned short* ah = (unsigned short*)(W + 8388608);    // 4MB
  unsigned short* al = (unsigned short*)(W + 12582912);   // 4MB
  float* ctx   = (float*)(W + 8388608);
  float* qkv   = (float*)(W + 16777216);
  float* qb    = (float*)(W + 29360128);
  float* h2f   = (float*)(W + 37748736);
  float* kb    = (float*)(W + 46137344);
  float* vb    = (float*)(W + 48234496);
  // flash partial scratch (phase D; qkv/h2f regions dead then):
  float* Op1   = (float*)(W + 16777216);            // 8MB
  float* Ml    = (float*)(W + 25165824);            // 384KB
  float* Op2   = (float*)(W + 37748736);            // 8MB (h2f region)
  // ctx bf16 split (written by fmerge; qb region dead post-flash):
  unsigned short* cth = (unsigned short*)(W + 29360128);  // 4MB
  unsigned short* ctl = (unsigned short*)(W + 33554432);  // 4MB
  // qkv_w^T split (used at B; h2f/Op2 region scribbled at D -> safe order 0,B,D):
  unsigned short* qwt_h = (unsigned short*)(W + 37748736); // 3MB
  unsigned short* qwt_l = (unsigned short*)(W + 40894464); // 3MB (ends 44040192)
  // dense_w^T split (used at E; h2b region written at F -> safe):
  unsigned short* dwt_h = (unsigned short*)(W + 50331648); // 2MB
  unsigned short* dwt_l = (unsigned short*)(W + 52428800); // 2MB (ends 54525952)
  unsigned short* gu    = (unsigned short*)(W + 8388608);
  unsigned short* ybuf  = (unsigned short*)(W + 8388608);
  unsigned short* sgu   = (unsigned short*)(W + 16777216);
  unsigned short* sact  = (unsigned short*)(W + 0);
  unsigned short* sout  = (unsigned short*)(W + 46137344);
  unsigned short* h2b   = (unsigned short*)(W + 50331648);
  unsigned short* act   = (unsigned short*)(W + 54525952);
  unsigned short* w13t  = (unsigned short*)(W + 71303168);
  unsigned short* w2t   = (unsigned short*)(W + 138412032);
  unsigned short* wsgut = (unsigned short*)(W + 171966464);
  unsigned short* wsdt  = (unsigned short*)(W + 176160768);
  float* topkw = (float*)(W + 178257920);
  int* topki   = (int*)(W + 178290688);
  int* ptok    = (int*)(W + 178323456);
  int* t2p     = (int*)(W + 178356224);
  int* cnt     = (int*)(W + 178388992);
  int* offs    = (int*)(W + 178389056);
  int* cur     = (int*)(W + 178389184);

  // 0. weight cvt + transpose -> bf16 B^T (FFN) and bf16x2 split B^T (QKV/dense)
  k_cvt_t<<<dim3(64,32,16), 256, 0, stream>>>(w13,  w13t,  1024, 2048);
  k_cvt_t<<<dim3(32,32,16), 256, 0, stream>>>(w2,   w2t,   1024, 1024);
  k_cvt_t<<<dim3(64,32,1),  256, 0, stream>>>(wsgu, wsgut, 1024, 2048);
  k_cvt_t<<<dim3(32,32,1),  256, 0, stream>>>(wsd,  wsdt,  1024, 1024);
  k_cvt_t3<<<dim3(48,32,1), 256, 0, stream>>>(qkvw, qwt_h, qwt_l, 1024, 1536);
  k_cvt_t3<<<dim3(32,32,1), 256, 0, stream>>>(dw,   dwt_h, dwt_l, 1024, 1024);
  // A. resid + rmsnorm -> bf16x2 split A
  k_add_rmsnorm<<<T_TOK, 256, 0, stream>>>(hs, rsd, ln1, resid, ah, al);
  // B. qkv = h @ qkv_w (bf16x3 MFMA, fp32 out)
  gemm_mfma3<0><<<dim3(QKV_DIM/128, T_TOK/128), 256, 0, stream>>>(
      ah, al, 1024, qwt_h, qwt_l, 1024, qkv, QKV_DIM, nullptr, 1024);
  // C. q/k norm + rope
  k_qkv_post<<<dim3(12, T_TOK), 64, 0, stream>>>(qkv, qnw, knw, pos, qb, kb, vb);
  // D. flash attention: 512 equal chains + merge (emits ctx bf16x2 split)
  k_flash<<<512, 256, 0, stream>>>(qb, kb, vb, ctx, Op1, Op2, Ml);
  k_fmerge<<<4096, 256, 0, stream>>>(ctx, Op1, Op2, Ml, cth, ctl);
  // E. resid2 = ctx @ dense_w + resid -> out1 (bf16x3 MFMA, fp32 out)
  gemm_mfma3<1><<<dim3(H_DIM/128, T_TOK/128), 256, 0, stream>>>(
      cth, ctl, 1024, dwt_h, dwt_l, 1024, out1, H_DIM, resid, 1024);
  // F. h2 = rmsnorm(out1)
  k_rms2<<<T_TOK, 256, 0, stream>>>(out1, ln2, h2f, h2b);
  // G. router
  k_zero<<<1, 64, 0, stream>>>(cnt);
  k_router<<<T_TOK, 256, 0, stream>>>(h2f, gw, eb, topki, topkw, cnt);
  k_scan<<<1, 64, 0, stream>>>(cnt, offs, cur);
  k_scatter<<<NPAIR/256, 256, 0, stream>>>(topki, cur, ptok, t2p);
  // H. shared expert (MFMA)
  gemm_mfma<false,false><<<dim3(16,16,1), 256, 0, stream>>>(
      h2b, 1024, wsgut, 1024, 0, sgu, 2048, nullptr, nullptr, T_TOK, 1024);
  k_silu<<<T_TOK, 256, 0, stream>>>(sgu, sact);
  gemm_mfma<false,false><<<dim3(8,16,1), 256, 0, stream>>>(
      sact, 1024, wsdt, 1024, 0, sout, 1024, nullptr, nullptr, T_TOK, 1024);
  // I. MoE expert FFN (MFMA, grouped)
  gemm_mfma<true,true><<<dim3(16,64,16), 256, 0, stream>>>(
      h2b, 1024, w13t, 1024, (long long)2048*1024, gu, 2048, ptok, offs, 0, 1024);
  k_silu<<<NPAIR, 256, 0, stream>>>(gu, act);
  gemm_mfma<true,false><<<dim3(8,64,16), 256, 0, stream>>>(
      act, 1024, w2t, 1024, (long long)1024*1024, ybuf, 1024, nullptr, offs, 0, 1024);
  // K. combine -> out0
  k_combine<<<T_TOK, 256, 0, stream>>>(ybuf, sout, t2p, topkw, out0);
}